// Round 1
// baseline (1949.990 us; speedup 1.0000x reference)
//
#include <hip/hip_runtime.h>
#include <math.h>

#define EMBED 768
#define DI 1536            // d_inner
#define DSTATE 16
#define DCONV 4
#define DTRANK 48
#define FF 3072
#define BATCH 2
#define SEQ 1024
#define NROWS (BATCH*SEQ)  // 2048

// ---------------------------------------------------------------------------
// Generic tiled f32 GEMM:  C[M,N] = A[M,lda] (rows, first K cols) * W[N,K]^T
// EPI: 0 none, 1 softplus(acc+bias), 2 acc+resid, 3 gelu_tanh(acc+bias),
//      4 acc+bias+resid
// ---------------------------------------------------------------------------
template<int EPI>
__global__ __launch_bounds__(256)
void gemm_tn(const float* __restrict__ A, int lda,
             const float* __restrict__ W,
             float* __restrict__ C, int M, int N, int K,
             const float* __restrict__ bias,
             const float* __restrict__ resid)
{
    const int BM = 64, BN = 64, BK = 16;
    __shared__ float As[BK][BM + 1];
    __shared__ float Ws[BK][BN + 1];

    const int tid = threadIdx.x;
    const int bm = blockIdx.y * BM;
    const int bn = blockIdx.x * BN;
    const int tx = tid & 15;        // 16 cols of threads
    const int ty = tid >> 4;        // 16 rows of threads
    const int kx = tid & 15;        // k index for staging
    const int ry = tid >> 4;        // row base for staging

    float acc[4][4] = {};

    for (int k0 = 0; k0 < K; k0 += BK) {
        #pragma unroll
        for (int p = 0; p < 4; ++p) {
            int m = ry + p * 16;
            As[kx][m] = A[(size_t)(bm + m) * lda + k0 + kx];
        }
        #pragma unroll
        for (int p = 0; p < 4; ++p) {
            int n = ry + p * 16;
            float v = 0.f;
            if (bn + n < N) v = W[(size_t)(bn + n) * K + k0 + kx];
            Ws[kx][n] = v;
        }
        __syncthreads();
        #pragma unroll
        for (int kk = 0; kk < BK; ++kk) {
            float a[4], b[4];
            #pragma unroll
            for (int i = 0; i < 4; ++i) a[i] = As[kk][ty * 4 + i];
            #pragma unroll
            for (int j = 0; j < 4; ++j) b[j] = Ws[kk][tx * 4 + j];
            #pragma unroll
            for (int i = 0; i < 4; ++i)
                #pragma unroll
                for (int j = 0; j < 4; ++j)
                    acc[i][j] += a[i] * b[j];
        }
        __syncthreads();
    }

    #pragma unroll
    for (int i = 0; i < 4; ++i) {
        int m = bm + ty * 4 + i;
        #pragma unroll
        for (int j = 0; j < 4; ++j) {
            int n = bn + tx * 4 + j;
            if (n >= N) continue;
            float v = acc[i][j];
            if (EPI == 1) {                 // softplus(acc + bias)
                v += bias[n];
                v = (v > 20.f) ? v : log1pf(expf(v));
            } else if (EPI == 2) {          // + resid
                v += resid[(size_t)m * N + n];
            } else if (EPI == 3) {          // gelu_tanh(acc + bias)
                v += bias[n];
                float t = 0.7978845608028654f * (v + 0.044715f * v * v * v);
                v = 0.5f * v * (1.f + tanhf(t));
            } else if (EPI == 4) {          // + bias + resid
                v += bias[n] + resid[(size_t)m * N + n];
            }
            C[(size_t)m * N + n] = v;
        }
    }
}

// ---------------------------------------------------------------------------
// Causal depthwise conv(4) + bias + SiLU.  xin = first half of xz rows.
// ---------------------------------------------------------------------------
__global__ __launch_bounds__(256)
void conv_silu_k(const float* __restrict__ xz, const float* __restrict__ cw,
                 const float* __restrict__ cb, float* __restrict__ xc)
{
    int idx = blockIdx.x * 256 + threadIdx.x;           // over B*L*DI
    if (idx >= BATCH * SEQ * DI) return;
    int d  = idx % DI;
    int bt = idx / DI;
    int t  = bt % SEQ;
    int b  = bt / SEQ;

    float w0 = cw[d * 4 + 0], w1 = cw[d * 4 + 1], w2 = cw[d * 4 + 2], w3 = cw[d * 4 + 3];
    const float* base = xz + ((size_t)b * SEQ) * (2 * DI) + d;   // xin col d
    float acc = cb[d];
    if (t - 3 >= 0) acc += w0 * base[(size_t)(t - 3) * (2 * DI)];
    if (t - 2 >= 0) acc += w1 * base[(size_t)(t - 2) * (2 * DI)];
    if (t - 1 >= 0) acc += w2 * base[(size_t)(t - 1) * (2 * DI)];
    acc += w3 * base[(size_t)t * (2 * DI)];
    xc[idx] = acc / (1.f + expf(-acc));                 // silu
}

// ---------------------------------------------------------------------------
// SSM scan, fused with D-skip and SiLU(z) gating.
// lane = dsub*16 + n; each wave owns 4 channels; block (256 thr) owns 16.
// grid: (DI/16, BATCH)
// ---------------------------------------------------------------------------
__global__ __launch_bounds__(256)
void ssm_scan_k(const float* __restrict__ delta, const float* __restrict__ xc,
                const float* __restrict__ xdbl,  const float* __restrict__ A_log,
                const float* __restrict__ Dp,    const float* __restrict__ xz,
                float* __restrict__ y)
{
    const int b     = blockIdx.y;
    const int dbase = blockIdx.x * 16;
    const int lane  = threadIdx.x & 63;
    const int wave  = threadIdx.x >> 6;
    const int dsub  = lane >> 4;
    const int n     = lane & 15;
    const int d     = dbase + wave * 4 + dsub;

    const float Adn = -expf(A_log[d * DSTATE + n]);
    const float Dd  = Dp[d];

    const float* drow  = delta + (size_t)b * SEQ * DI + d;
    const float* xcrow = xc    + (size_t)b * SEQ * DI + d;
    const float* bcrow = xdbl  + (size_t)b * SEQ * 80 + DTRANK + n;   // B; C at +16
    const float* zrow  = xz    + (size_t)b * SEQ * (2 * DI) + DI + d;
    float*       yrow  = y     + (size_t)b * SEQ * DI + d;

    float h = 0.f;
    for (int t = 0; t < SEQ; ++t) {
        float dl = drow[(size_t)t * DI];
        float xv = xcrow[(size_t)t * DI];
        float Bv = bcrow[(size_t)t * 80];
        float Cv = bcrow[(size_t)t * 80 + DSTATE];
        float dA = expf(dl * Adn);
        h = dA * h + dl * Bv * xv;
        float py = h * Cv;
        py += __shfl_xor(py, 1);
        py += __shfl_xor(py, 2);
        py += __shfl_xor(py, 4);
        py += __shfl_xor(py, 8);
        if (n == 0) {
            float yv = py + xv * Dd;
            float zv = zrow[(size_t)t * (2 * DI)];
            yv *= zv / (1.f + expf(-zv));
            yrow[(size_t)t * DI] = yv;
        }
    }
}

// ---------------------------------------------------------------------------
// LayerNorm over last dim = 768. One 256-thread block per row.
// ---------------------------------------------------------------------------
__global__ __launch_bounds__(256)
void layernorm_k(const float* __restrict__ in, const float* __restrict__ w,
                 const float* __restrict__ bb, float* __restrict__ out)
{
    const int row = blockIdx.x;
    const float* xr = in + (size_t)row * EMBED;
    const int i0 = threadIdx.x, i1 = i0 + 256, i2 = i0 + 512;
    float v0 = xr[i0], v1 = xr[i1], v2 = xr[i2];
    float s  = v0 + v1 + v2;
    float s2 = v0 * v0 + v1 * v1 + v2 * v2;
    #pragma unroll
    for (int m = 1; m < 64; m <<= 1) {
        s  += __shfl_xor(s,  m);
        s2 += __shfl_xor(s2, m);
    }
    __shared__ float sh1[4], sh2[4];
    int wv = threadIdx.x >> 6;
    if ((threadIdx.x & 63) == 0) { sh1[wv] = s; sh2[wv] = s2; }
    __syncthreads();
    float S1 = sh1[0] + sh1[1] + sh1[2] + sh1[3];
    float S2 = sh2[0] + sh2[1] + sh2[2] + sh2[3];
    float mu  = S1 * (1.f / EMBED);
    float var = S2 * (1.f / EMBED) - mu * mu;
    float rs  = rsqrtf(var + 1e-5f);
    float* orow = out + (size_t)row * EMBED;
    orow[i0] = (v0 - mu) * rs * w[i0] + bb[i0];
    orow[i1] = (v1 - mu) * rs * w[i1] + bb[i1];
    orow[i2] = (v2 - mu) * rs * w[i2] + bb[i2];
}

// ---------------------------------------------------------------------------
extern "C" void kernel_launch(void* const* d_in, const int* in_sizes, int n_in,
                              void* d_out, int out_size, void* d_ws, size_t ws_size,
                              hipStream_t stream)
{
    const float* x         = (const float*)d_in[0];
    const float* in_proj_w = (const float*)d_in[1];
    const float* conv_w    = (const float*)d_in[2];
    const float* conv_b    = (const float*)d_in[3];
    const float* x_proj_w  = (const float*)d_in[4];
    const float* dt_proj_w = (const float*)d_in[5];
    const float* dt_proj_b = (const float*)d_in[6];
    const float* A_log     = (const float*)d_in[7];
    const float* D_param   = (const float*)d_in[8];
    const float* out_proj_w= (const float*)d_in[9];
    const float* ln1_w     = (const float*)d_in[10];
    const float* ln1_b     = (const float*)d_in[11];
    const float* ln2_w     = (const float*)d_in[12];
    const float* ln2_b     = (const float*)d_in[13];
    const float* ffn_w1    = (const float*)d_in[14];
    const float* ffn_b1    = (const float*)d_in[15];
    const float* ffn_w2    = (const float*)d_in[16];
    const float* ffn_b2    = (const float*)d_in[17];
    float* out = (float*)d_out;

    float* ws = (float*)d_ws;
    float* xz    = ws;                           // [2048,3072]
    float* xc    = xz    + (size_t)NROWS * (2*DI);   // [2048,1536]
    float* xdbl  = xc    + (size_t)NROWS * DI;       // [2048,80]
    float* delta = xdbl  + (size_t)NROWS * 80;       // [2048,1536]
    float* yb    = delta + (size_t)NROWS * DI;       // [2048,1536]
    float* hres  = yb    + (size_t)NROWS * DI;       // [2048,768]
    float* x1    = hres  + (size_t)NROWS * EMBED;    // [2048,768]
    float* ores  = x1    + (size_t)NROWS * EMBED;    // [2048,768]
    float* f     = xz;                               // reuse xz after scan

    dim3 blk(256);
    dim3 gM(0, NROWS / 64);

    // 1. in_proj: xz = x @ in_proj_w^T   [2048,3072]
    gM.x = (2 * DI) / 64;
    gemm_tn<0><<<gM, blk, 0, stream>>>(x, EMBED, in_proj_w, xz, NROWS, 2 * DI, EMBED, nullptr, nullptr);

    // 2. conv + silu -> xc
    conv_silu_k<<<(BATCH * SEQ * DI) / 256, blk, 0, stream>>>(xz, conv_w, conv_b, xc);

    // 3. x_proj: xdbl = xc @ x_proj_w^T  [2048,80]
    gM.x = (80 + 63) / 64;
    gemm_tn<0><<<gM, blk, 0, stream>>>(xc, DI, x_proj_w, xdbl, NROWS, 80, DI, nullptr, nullptr);

    // 4. dt_proj + softplus: delta = softplus(xdbl[:, :48] @ dt_proj_w^T + b) [2048,1536]
    gM.x = DI / 64;
    gemm_tn<1><<<gM, blk, 0, stream>>>(xdbl, 80, dt_proj_w, delta, NROWS, DI, DTRANK, dt_proj_b, nullptr);

    // 5. fused scan + D skip + silu(z) gating -> yb
    ssm_scan_k<<<dim3(DI / 16, BATCH), blk, 0, stream>>>(delta, xc, xdbl, A_log, D_param, xz, yb);

    // 6. out_proj + residual: hres = yb @ out_proj_w^T + x   [2048,768]
    gM.x = EMBED / 64;
    gemm_tn<2><<<gM, blk, 0, stream>>>(yb, DI, out_proj_w, hres, NROWS, EMBED, DI, nullptr, x);

    // 7. LN1 -> x1
    layernorm_k<<<NROWS, blk, 0, stream>>>(hres, ln1_w, ln1_b, x1);

    // 8. FFN1 + gelu: f = gelu(x1 @ ffn_w1^T + b1)  [2048,3072]
    gM.x = FF / 64;
    gemm_tn<3><<<gM, blk, 0, stream>>>(x1, EMBED, ffn_w1, f, NROWS, FF, EMBED, ffn_b1, nullptr);

    // 9. FFN2 + bias + resid: ores = f @ ffn_w2^T + b2 + x1  [2048,768]
    gM.x = EMBED / 64;
    gemm_tn<4><<<gM, blk, 0, stream>>>(f, FF, ffn_w2, ores, NROWS, EMBED, FF, ffn_b2, x1);

    // 10. LN2 -> out
    layernorm_k<<<NROWS, blk, 0, stream>>>(ores, ln2_w, ln2_b, out);
}

// Round 2
// 524.239 us; speedup vs baseline: 3.7197x; 3.7197x over previous
//
#include <hip/hip_runtime.h>
#include <math.h>

#define EMBED 768
#define DI 1536
#define DSTATE 16
#define DCONV 4
#define DTRANK 48
#define FF 3072
#define BATCH 2
#define SEQ 1024
#define NROWS (BATCH*SEQ)
#define TCH 128
#define NCH (SEQ/TCH)

typedef __bf16 bf16x8 __attribute__((ext_vector_type(8)));
typedef float f32x4 __attribute__((ext_vector_type(4)));
typedef unsigned int u32x4 __attribute__((ext_vector_type(4)));

static __device__ __forceinline__ unsigned short f2b(float f) {
    union { float f; unsigned u; } v; v.f = f;
    unsigned r = v.u + 0x7FFFu + ((v.u >> 16) & 1u);
    return (unsigned short)(r >> 16);
}
static __device__ __forceinline__ float b2f(unsigned short s) {
    union { unsigned u; float f; } v; v.u = ((unsigned)s) << 16;
    return v.f;
}

// ---------------------------------------------------------------------------
// bf16 MFMA GEMM: C[M,N] = A[M,K](bf16) @ W[N,K](bf16)^T, f32 accum.
// 128x128 tile, BK=32, 4 waves each owning 64x64 (4x4 frags of 16x16x32).
// EPI: 2 +resid(f32)->C ; 3 gelu(acc+bias)->Cb(bf16) ; 4 +bias+resid->C ;
//      5 split: col<DI -> C(xin,f32, stride DI), col>=DI -> Cb(z,bf16, stride DI)
// ---------------------------------------------------------------------------
template<int EPI>
__global__ __launch_bounds__(256)
void gemm_mfma(const unsigned short* __restrict__ A,
               const unsigned short* __restrict__ W,
               float* __restrict__ C, unsigned short* __restrict__ Cb,
               int M, int N, int K,
               const float* __restrict__ bias,
               const float* __restrict__ resid)
{
    __shared__ alignas(16) unsigned short As[128 * 40];   // 32 k + 8 pad per row
    __shared__ alignas(16) unsigned short Ws[128 * 40];
    const int tid  = threadIdx.x;
    const int lane = tid & 63, wave = tid >> 6;
    const int wr = (wave >> 1) * 64, wc = (wave & 1) * 64;
    const int bm = blockIdx.y * 128, bn = blockIdx.x * 128;
    const int ln = lane & 15, lg = lane >> 4;
    const int r = tid >> 2, cg = tid & 3;

    f32x4 acc[4][4];
    #pragma unroll
    for (int i = 0; i < 4; ++i)
        #pragma unroll
        for (int j = 0; j < 4; ++j)
            acc[i][j] = (f32x4){0.f, 0.f, 0.f, 0.f};

    const unsigned short* gA0 = A + (size_t)(bm + r) * K + cg * 8;
    const unsigned short* gA1 = A + (size_t)(bm + r + 64) * K + cg * 8;
    const unsigned short* gW0 = W + (size_t)(bn + r) * K + cg * 8;
    const unsigned short* gW1 = W + (size_t)(bn + r + 64) * K + cg * 8;

    for (int k0 = 0; k0 < K; k0 += 32) {
        u32x4 a0 = *reinterpret_cast<const u32x4*>(gA0 + k0);
        u32x4 a1 = *reinterpret_cast<const u32x4*>(gA1 + k0);
        u32x4 w0 = *reinterpret_cast<const u32x4*>(gW0 + k0);
        u32x4 w1 = *reinterpret_cast<const u32x4*>(gW1 + k0);
        __syncthreads();
        *reinterpret_cast<u32x4*>(&As[r * 40 + cg * 8]) = a0;
        *reinterpret_cast<u32x4*>(&As[(r + 64) * 40 + cg * 8]) = a1;
        *reinterpret_cast<u32x4*>(&Ws[r * 40 + cg * 8]) = w0;
        *reinterpret_cast<u32x4*>(&Ws[(r + 64) * 40 + cg * 8]) = w1;
        __syncthreads();
        bf16x8 af[4], wf[4];
        #pragma unroll
        for (int i = 0; i < 4; ++i)
            af[i] = *reinterpret_cast<const bf16x8*>(&As[(wr + i * 16 + ln) * 40 + lg * 8]);
        #pragma unroll
        for (int j = 0; j < 4; ++j)
            wf[j] = *reinterpret_cast<const bf16x8*>(&Ws[(wc + j * 16 + ln) * 40 + lg * 8]);
        #pragma unroll
        for (int i = 0; i < 4; ++i)
            #pragma unroll
            for (int j = 0; j < 4; ++j)
                acc[i][j] = __builtin_amdgcn_mfma_f32_16x16x32_bf16(af[i], wf[j], acc[i][j], 0, 0, 0);
    }

    #pragma unroll
    for (int i = 0; i < 4; ++i) {
        #pragma unroll
        for (int j = 0; j < 4; ++j) {
            int col = bn + wc + j * 16 + ln;
            #pragma unroll
            for (int rr = 0; rr < 4; ++rr) {
                int row = bm + wr + i * 16 + lg * 4 + rr;
                float v = acc[i][j][rr];
                size_t o = (size_t)row * N + col;
                if (EPI == 2) {
                    C[o] = v + resid[o];
                } else if (EPI == 3) {
                    v += bias[col];
                    float t = 0.7978845608028654f * (v + 0.044715f * v * v * v);
                    Cb[o] = f2b(0.5f * v * (1.f + tanhf(t)));
                } else if (EPI == 4) {
                    C[o] = v + bias[col] + resid[o];
                } else if (EPI == 5) {
                    if (col < DI) C[(size_t)row * DI + col] = v;
                    else          Cb[(size_t)row * DI + col - DI] = f2b(v);
                } else {
                    C[o] = v;
                }
            }
        }
    }
}

// ---------------------------------------------------------------------------
// f32 tiled GEMM (kept for small x_proj / dt_proj).
// EPI: 0 none, 1 softplus(acc+bias)
// ---------------------------------------------------------------------------
template<int EPI>
__global__ __launch_bounds__(256)
void gemm_tn(const float* __restrict__ A, int lda,
             const float* __restrict__ W,
             float* __restrict__ C, int M, int N, int K,
             const float* __restrict__ bias)
{
    const int BK = 16;
    __shared__ float As[BK][64 + 1];
    __shared__ float Ws[BK][64 + 1];
    const int tid = threadIdx.x;
    const int bm = blockIdx.y * 64, bn = blockIdx.x * 64;
    const int tx = tid & 15, ty = tid >> 4;
    const int kx = tid & 15, ry = tid >> 4;
    float acc[4][4] = {};

    for (int k0 = 0; k0 < K; k0 += BK) {
        #pragma unroll
        for (int p = 0; p < 4; ++p) {
            int m = ry + p * 16;
            As[kx][m] = A[(size_t)(bm + m) * lda + k0 + kx];
            int n = m;
            float v = 0.f;
            if (bn + n < N) v = W[(size_t)(bn + n) * K + k0 + kx];
            Ws[kx][n] = v;
        }
        __syncthreads();
        #pragma unroll
        for (int kk = 0; kk < BK; ++kk) {
            float a[4], b[4];
            #pragma unroll
            for (int i = 0; i < 4; ++i) a[i] = As[kk][ty * 4 + i];
            #pragma unroll
            for (int j = 0; j < 4; ++j) b[j] = Ws[kk][tx * 4 + j];
            #pragma unroll
            for (int i = 0; i < 4; ++i)
                #pragma unroll
                for (int j = 0; j < 4; ++j)
                    acc[i][j] += a[i] * b[j];
        }
        __syncthreads();
    }
    #pragma unroll
    for (int i = 0; i < 4; ++i) {
        int m = bm + ty * 4 + i;
        #pragma unroll
        for (int j = 0; j < 4; ++j) {
            int n = bn + tx * 4 + j;
            if (n >= N) continue;
            float v = acc[i][j];
            if (EPI == 1) {
                v += bias[n];
                v = (v > 20.f) ? v : log1pf(expf(v));
            }
            C[(size_t)m * N + n] = v;
        }
    }
}

// ---------------------------------------------------------------------------
// f32 -> bf16 conversion of x + 4 weight matrices, one fused kernel.
// ---------------------------------------------------------------------------
__global__ __launch_bounds__(256)
void cvt5_k(const float* __restrict__ x,  const float* __restrict__ w1,
            const float* __restrict__ w2, const float* __restrict__ w3,
            const float* __restrict__ w4,
            unsigned short* __restrict__ xb,  unsigned short* __restrict__ w1b,
            unsigned short* __restrict__ w2b, unsigned short* __restrict__ w3b,
            unsigned short* __restrict__ w4b)
{
    size_t i4 = ((size_t)blockIdx.x * 256 + threadIdx.x) * 4;
    const float* src; unsigned short* dst; size_t off;
    if      (i4 < 1572864u) { src = x;  dst = xb;  off = i4; }
    else if (i4 < 3932160u) { src = w1; dst = w1b; off = i4 - 1572864u; }
    else if (i4 < 5111808u) { src = w2; dst = w2b; off = i4 - 3932160u; }
    else if (i4 < 7471104u) { src = w3; dst = w3b; off = i4 - 5111808u; }
    else                    { src = w4; dst = w4b; off = i4 - 7471104u; }
    float4 v = *reinterpret_cast<const float4*>(src + off);
    ushort4 u;
    u.x = f2b(v.x); u.y = f2b(v.y); u.z = f2b(v.z); u.w = f2b(v.w);
    *reinterpret_cast<ushort4*>(dst + off) = u;
}

// ---------------------------------------------------------------------------
// Causal depthwise conv(4) + bias + SiLU; reads xin [B,L,DI] f32.
// ---------------------------------------------------------------------------
__global__ __launch_bounds__(256)
void conv_silu_k(const float* __restrict__ xin, const float* __restrict__ cw,
                 const float* __restrict__ cb, float* __restrict__ xc)
{
    int idx = blockIdx.x * 256 + threadIdx.x;
    int d  = idx % DI;
    int bt = idx / DI;
    int t  = bt % SEQ, b = bt / SEQ;
    float w0 = cw[d*4], w1 = cw[d*4+1], w2 = cw[d*4+2], w3 = cw[d*4+3];
    const float* base = xin + ((size_t)b * SEQ) * DI + d;
    float acc = cb[d];
    if (t >= 3) acc += w0 * base[(size_t)(t - 3) * DI];
    if (t >= 2) acc += w1 * base[(size_t)(t - 2) * DI];
    if (t >= 1) acc += w2 * base[(size_t)(t - 1) * DI];
    acc += w3 * base[(size_t)t * DI];
    xc[idx] = acc / (1.f + expf(-acc));
}

// ---------------------------------------------------------------------------
// Chunked SSM scan, phase A: per-chunk local scan from h0=0.
// Outputs per (b,chunk,d,n): final local h and prod(dA).
// Block: 16 d-channels x chunk of 128 t. grid (96, 8, 2).
// ---------------------------------------------------------------------------
__global__ __launch_bounds__(256)
void scan_a(const float* __restrict__ delta, const float* __restrict__ xc,
            const float* __restrict__ xdbl,  const float* __restrict__ A_log,
            float* __restrict__ hfin, float* __restrict__ aprod)
{
    const int dblk = blockIdx.x, ch = blockIdx.y, b = blockIdx.z;
    const int d0 = dblk * 16, t0 = ch * TCH;
    __shared__ float del_s[TCH][17];
    __shared__ float xcs[TCH][17];
    __shared__ float b_s[TCH][16];
    const int tid = threadIdx.x;
    const int sr = tid >> 4, sc = tid & 15;
    for (int p = 0; p < 8; ++p) {
        int t = p * 16 + sr;
        size_t rowo = (size_t)(b * SEQ + t0 + t);
        del_s[t][sc] = delta[rowo * DI + d0 + sc];
        xcs[t][sc]   = xc[rowo * DI + d0 + sc];
        b_s[t][sc]   = xdbl[rowo * 80 + DTRANK + sc];
    }
    __syncthreads();
    const int lane = tid & 63, wave = tid >> 6;
    const int wd = wave * 4 + (lane >> 4), n = lane & 15;
    const int d = d0 + wd;
    const float Adn = -expf(A_log[d * DSTATE + n]);
    float h = 0.f, ap = 1.f;
    for (int t = 0; t < TCH; ++t) {
        float dl = del_s[t][wd];
        float dA = expf(dl * Adn);
        h = dA * h + dl * b_s[t][n] * xcs[t][wd];
        ap *= dA;
    }
    size_t o = ((size_t)(b * NCH + ch) * DI + d) * DSTATE + n;
    hfin[o] = h; aprod[o] = ap;
}

// ---------------------------------------------------------------------------
// Phase C: recombine chunk prefixes, rerun scan with correct h0, produce
// gated y (bf16). Fused D-skip + SiLU(z).
// ---------------------------------------------------------------------------
__global__ __launch_bounds__(256)
void scan_c(const float* __restrict__ delta, const float* __restrict__ xc,
            const float* __restrict__ xdbl,  const float* __restrict__ A_log,
            const float* __restrict__ Dp,    const unsigned short* __restrict__ zb,
            const float* __restrict__ hfin,  const float* __restrict__ aprod,
            unsigned short* __restrict__ yb)
{
    const int dblk = blockIdx.x, ch = blockIdx.y, b = blockIdx.z;
    const int d0 = dblk * 16, t0 = ch * TCH;
    __shared__ float del_s[TCH][17];
    __shared__ float xcs[TCH][17];
    __shared__ float b_s[TCH][16];
    __shared__ float c_s[TCH][16];
    __shared__ float z_s[TCH][17];
    __shared__ unsigned short y_s[TCH][16];
    const int tid = threadIdx.x;
    const int sr = tid >> 4, sc = tid & 15;
    for (int p = 0; p < 8; ++p) {
        int t = p * 16 + sr;
        size_t rowo = (size_t)(b * SEQ + t0 + t);
        del_s[t][sc] = delta[rowo * DI + d0 + sc];
        xcs[t][sc]   = xc[rowo * DI + d0 + sc];
        b_s[t][sc]   = xdbl[rowo * 80 + DTRANK + sc];
        c_s[t][sc]   = xdbl[rowo * 80 + DTRANK + DSTATE + sc];
        z_s[t][sc]   = b2f(zb[rowo * DI + d0 + sc]);
    }
    __syncthreads();
    const int lane = tid & 63, wave = tid >> 6;
    const int wd = wave * 4 + (lane >> 4), n = lane & 15;
    const int d = d0 + wd;
    const float Adn = -expf(A_log[d * DSTATE + n]);
    const float Dd = Dp[d];
    float h = 0.f;
    for (int cc = 0; cc < ch; ++cc) {
        size_t o = ((size_t)(b * NCH + cc) * DI + d) * DSTATE + n;
        h = aprod[o] * h + hfin[o];
    }
    for (int t = 0; t < TCH; ++t) {
        float dl = del_s[t][wd], xv = xcs[t][wd];
        float dA = expf(dl * Adn);
        h = dA * h + dl * b_s[t][n] * xv;
        float py = h * c_s[t][n];
        py += __shfl_xor(py, 1);
        py += __shfl_xor(py, 2);
        py += __shfl_xor(py, 4);
        py += __shfl_xor(py, 8);
        if (n == 0) {
            float yv = py + xv * Dd;
            float zv = z_s[t][wd];
            y_s[t][wd] = f2b(yv * zv / (1.f + expf(-zv)));
        }
    }
    __syncthreads();
    for (int p = 0; p < 8; ++p) {
        int t = p * 16 + sr;
        yb[(size_t)(b * SEQ + t0 + t) * DI + d0 + sc] = y_s[t][sc];
    }
}

// ---------------------------------------------------------------------------
// LayerNorm over 768, optional bf16 secondary output.
// ---------------------------------------------------------------------------
__global__ __launch_bounds__(256)
void layernorm_k(const float* __restrict__ in, const float* __restrict__ w,
                 const float* __restrict__ bb, float* __restrict__ out,
                 unsigned short* __restrict__ outb)
{
    const int row = blockIdx.x;
    const float* xr = in + (size_t)row * EMBED;
    const int i0 = threadIdx.x, i1 = i0 + 256, i2 = i0 + 512;
    float v0 = xr[i0], v1 = xr[i1], v2 = xr[i2];
    float s  = v0 + v1 + v2;
    float s2 = v0 * v0 + v1 * v1 + v2 * v2;
    #pragma unroll
    for (int m = 1; m < 64; m <<= 1) {
        s  += __shfl_xor(s,  m);
        s2 += __shfl_xor(s2, m);
    }
    __shared__ float sh1[4], sh2[4];
    int wv = threadIdx.x >> 6;
    if ((threadIdx.x & 63) == 0) { sh1[wv] = s; sh2[wv] = s2; }
    __syncthreads();
    float S1 = sh1[0] + sh1[1] + sh1[2] + sh1[3];
    float S2 = sh2[0] + sh2[1] + sh2[2] + sh2[3];
    float mu  = S1 * (1.f / EMBED);
    float var = S2 * (1.f / EMBED) - mu * mu;
    float rs  = rsqrtf(var + 1e-5f);
    float* orow = out + (size_t)row * EMBED;
    float o0 = (v0 - mu) * rs * w[i0] + bb[i0];
    float o1 = (v1 - mu) * rs * w[i1] + bb[i1];
    float o2 = (v2 - mu) * rs * w[i2] + bb[i2];
    orow[i0] = o0; orow[i1] = o1; orow[i2] = o2;
    if (outb) {
        unsigned short* obr = outb + (size_t)row * EMBED;
        obr[i0] = f2b(o0); obr[i1] = f2b(o1); obr[i2] = f2b(o2);
    }
}

// ---------------------------------------------------------------------------
extern "C" void kernel_launch(void* const* d_in, const int* in_sizes, int n_in,
                              void* d_out, int out_size, void* d_ws, size_t ws_size,
                              hipStream_t stream)
{
    const float* x         = (const float*)d_in[0];
    const float* in_proj_w = (const float*)d_in[1];
    const float* conv_w    = (const float*)d_in[2];
    const float* conv_b    = (const float*)d_in[3];
    const float* x_proj_w  = (const float*)d_in[4];
    const float* dt_proj_w = (const float*)d_in[5];
    const float* dt_proj_b = (const float*)d_in[6];
    const float* A_log     = (const float*)d_in[7];
    const float* D_param   = (const float*)d_in[8];
    const float* out_proj_w= (const float*)d_in[9];
    const float* ln1_w     = (const float*)d_in[10];
    const float* ln1_b     = (const float*)d_in[11];
    const float* ln2_w     = (const float*)d_in[12];
    const float* ln2_b     = (const float*)d_in[13];
    const float* ffn_w1    = (const float*)d_in[14];
    const float* ffn_b1    = (const float*)d_in[15];
    const float* ffn_w2    = (const float*)d_in[16];
    const float* ffn_b2    = (const float*)d_in[17];
    float* out = (float*)d_out;

    char* Wp = (char*)d_ws;
    // workspace layout (bytes); aliases reuse dead regions
    float*          xin   = (float*)         (Wp + 0);          // 12582912
    unsigned short* zbuf  = (unsigned short*)(Wp + 12582912);   // 6291456
    float*          xc    = (float*)         (Wp + 18874368);   // 12582912
    float*          xdbl  = (float*)         (Wp + 31457280);   // 655360
    float*          delta = (float*)         (Wp + 32112640);   // 12582912
    unsigned short* ybb   = (unsigned short*)(Wp + 44695552);   // 6291456
    float*          hres  = (float*)         (Wp + 50987008);   // 6291456
    float*          hfin  = (float*)         (Wp + 57278464);   // 786432
    float*          aprod = (float*)         (Wp + 58064896);   // 786432
    unsigned short* xb    = (unsigned short*)(Wp + 58851328);   // 3145728
    unsigned short* wib   = (unsigned short*)(Wp + 61997056);   // 4718592
    unsigned short* wob   = (unsigned short*)(Wp + 66715648);   // 2359296
    unsigned short* wf1b  = (unsigned short*)(Wp + 69074944);   // 4718592
    unsigned short* wf2b  = (unsigned short*)(Wp + 73793536);   // 4718592
    // aliases (regions dead by the time these are written):
    unsigned short* fbf   = (unsigned short*)(Wp + 0);          // ffn1 out, aliases xin
    float*          ores  = (float*)         (Wp + 12582912);   // ffn2 out, aliases zbuf
    float*          x1    = (float*)         (Wp + 32112640);   // LN1 out, aliases delta
    unsigned short* x1b   = (unsigned short*)(Wp + 58851328);   // LN1 bf16, aliases xb

    dim3 blk(256);

    // 1. bf16 conversions: x, in_proj_w, out_proj_w, ffn_w1, ffn_w2
    cvt5_k<<<9600, blk, 0, stream>>>(x, in_proj_w, out_proj_w, ffn_w1, ffn_w2,
                                     xb, wib, wob, wf1b, wf2b);

    // 2. in_proj (MFMA, split epilogue): xin f32 + z bf16
    gemm_mfma<5><<<dim3(24, 16), blk, 0, stream>>>(xb, wib, xin, zbuf,
                                                   NROWS, 2 * DI, EMBED, nullptr, nullptr);

    // 3. conv + silu -> xc f32
    conv_silu_k<<<(BATCH * SEQ * DI) / 256, blk, 0, stream>>>(xin, conv_w, conv_b, xc);

    // 4. x_proj (f32): xdbl = xc @ x_proj_w^T  [2048,80]
    gemm_tn<0><<<dim3(2, 32), blk, 0, stream>>>(xc, DI, x_proj_w, xdbl, NROWS, 80, DI, nullptr);

    // 5. dt_proj + softplus (f32): delta [2048,1536]
    gemm_tn<1><<<dim3(24, 32), blk, 0, stream>>>(xdbl, 80, dt_proj_w, delta, NROWS, DI, DTRANK, dt_proj_b);

    // 6-7. chunked scan
    scan_a<<<dim3(96, NCH, BATCH), blk, 0, stream>>>(delta, xc, xdbl, A_log, hfin, aprod);
    scan_c<<<dim3(96, NCH, BATCH), blk, 0, stream>>>(delta, xc, xdbl, A_log, D_param, zbuf,
                                                     hfin, aprod, ybb);

    // 8. out_proj (MFMA) + resid x -> hres f32
    gemm_mfma<2><<<dim3(6, 16), blk, 0, stream>>>(ybb, wob, hres, nullptr,
                                                  NROWS, EMBED, DI, nullptr, x);

    // 9. LN1 -> x1 f32 + x1b bf16
    layernorm_k<<<NROWS, blk, 0, stream>>>(hres, ln1_w, ln1_b, x1, x1b);

    // 10. ffn1 (MFMA) + gelu -> fbf bf16
    gemm_mfma<3><<<dim3(24, 16), blk, 0, stream>>>(x1b, wf1b, nullptr, fbf,
                                                   NROWS, FF, EMBED, ffn_b1, nullptr);

    // 11. ffn2 (MFMA) + bias + resid x1 -> ores f32
    gemm_mfma<4><<<dim3(6, 16), blk, 0, stream>>>(fbf, wf2b, ores, nullptr,
                                                  NROWS, EMBED, FF, ffn_b2, x1);

    // 12. LN2 -> out
    layernorm_k<<<NROWS, blk, 0, stream>>>(ores, ln2_w, ln2_b, out, nullptr);
}

// Round 3
// 370.070 us; speedup vs baseline: 5.2692x; 1.4166x over previous
//
#include <hip/hip_runtime.h>
#include <math.h>

#define EMBED 768
#define DI 1536
#define DSTATE 16
#define DCONV 4
#define DTRANK 48
#define FF 3072
#define BATCH 2
#define SEQ 1024
#define NROWS (BATCH*SEQ)
#define TCH 128
#define NCH (SEQ/TCH)

typedef __bf16 bf16x8 __attribute__((ext_vector_type(8)));
typedef float f32x4 __attribute__((ext_vector_type(4)));
typedef unsigned int u32x4 __attribute__((ext_vector_type(4)));

static __device__ __forceinline__ unsigned short f2b(float f) {
    union { float f; unsigned u; } v; v.f = f;
    unsigned r = v.u + 0x7FFFu + ((v.u >> 16) & 1u);
    return (unsigned short)(r >> 16);
}
static __device__ __forceinline__ float b2f(unsigned short s) {
    union { unsigned u; float f; } v; v.u = ((unsigned)s) << 16;
    return v.f;
}

// ---------------------------------------------------------------------------
// bf16 MFMA GEMM: C[M,N] = A[M,K](bf16) @ W[N,K](bf16)^T, f32 accum.
// 128x128 tile, BK=32, 4 waves each owning 64x64 (4x4 frags of 16x16x32).
// EPI: 1 softplus(acc+bias)->C ; 2 +resid(f32)->C ; 3 gelu(acc+bias)->Cb ;
//      4 +bias+resid->C ; 5 split: col<DI -> C(f32), col>=DI -> Cb(bf16)
// ---------------------------------------------------------------------------
template<int EPI>
__global__ __launch_bounds__(256)
void gemm_mfma(const unsigned short* __restrict__ A,
               const unsigned short* __restrict__ W,
               float* __restrict__ C, unsigned short* __restrict__ Cb,
               int M, int N, int K,
               const float* __restrict__ bias,
               const float* __restrict__ resid)
{
    __shared__ alignas(16) unsigned short As[128 * 40];
    __shared__ alignas(16) unsigned short Ws[128 * 40];
    const int tid  = threadIdx.x;
    const int lane = tid & 63, wave = tid >> 6;
    const int wr = (wave >> 1) * 64, wc = (wave & 1) * 64;
    const int bm = blockIdx.y * 128, bn = blockIdx.x * 128;
    const int ln = lane & 15, lg = lane >> 4;
    const int r = tid >> 2, cg = tid & 3;

    f32x4 acc[4][4];
    #pragma unroll
    for (int i = 0; i < 4; ++i)
        #pragma unroll
        for (int j = 0; j < 4; ++j)
            acc[i][j] = (f32x4){0.f, 0.f, 0.f, 0.f};

    const unsigned short* gA0 = A + (size_t)(bm + r) * K + cg * 8;
    const unsigned short* gA1 = A + (size_t)(bm + r + 64) * K + cg * 8;
    const unsigned short* gW0 = W + (size_t)(bn + r) * K + cg * 8;
    const unsigned short* gW1 = W + (size_t)(bn + r + 64) * K + cg * 8;

    for (int k0 = 0; k0 < K; k0 += 32) {
        u32x4 a0 = *reinterpret_cast<const u32x4*>(gA0 + k0);
        u32x4 a1 = *reinterpret_cast<const u32x4*>(gA1 + k0);
        u32x4 w0 = *reinterpret_cast<const u32x4*>(gW0 + k0);
        u32x4 w1 = *reinterpret_cast<const u32x4*>(gW1 + k0);
        __syncthreads();
        *reinterpret_cast<u32x4*>(&As[r * 40 + cg * 8]) = a0;
        *reinterpret_cast<u32x4*>(&As[(r + 64) * 40 + cg * 8]) = a1;
        *reinterpret_cast<u32x4*>(&Ws[r * 40 + cg * 8]) = w0;
        *reinterpret_cast<u32x4*>(&Ws[(r + 64) * 40 + cg * 8]) = w1;
        __syncthreads();
        bf16x8 af[4], wf[4];
        #pragma unroll
        for (int i = 0; i < 4; ++i)
            af[i] = *reinterpret_cast<const bf16x8*>(&As[(wr + i * 16 + ln) * 40 + lg * 8]);
        #pragma unroll
        for (int j = 0; j < 4; ++j)
            wf[j] = *reinterpret_cast<const bf16x8*>(&Ws[(wc + j * 16 + ln) * 40 + lg * 8]);
        #pragma unroll
        for (int i = 0; i < 4; ++i)
            #pragma unroll
            for (int j = 0; j < 4; ++j)
                acc[i][j] = __builtin_amdgcn_mfma_f32_16x16x32_bf16(af[i], wf[j], acc[i][j], 0, 0, 0);
    }

    #pragma unroll
    for (int i = 0; i < 4; ++i) {
        #pragma unroll
        for (int j = 0; j < 4; ++j) {
            int col = bn + wc + j * 16 + ln;
            #pragma unroll
            for (int rr = 0; rr < 4; ++rr) {
                int row = bm + wr + i * 16 + lg * 4 + rr;
                float v = acc[i][j][rr];
                size_t o = (size_t)row * N + col;
                if (EPI == 1) {
                    v += bias[col];
                    C[o] = (v > 20.f) ? v : log1pf(expf(v));
                } else if (EPI == 2) {
                    C[o] = v + resid[o];
                } else if (EPI == 3) {
                    v += bias[col];
                    float t = 0.7978845608028654f * (v + 0.044715f * v * v * v);
                    Cb[o] = f2b(0.5f * v * (1.f + tanhf(t)));
                } else if (EPI == 4) {
                    C[o] = v + bias[col] + resid[o];
                } else if (EPI == 5) {
                    if (col < DI) C[(size_t)row * DI + col] = v;
                    else          Cb[(size_t)row * DI + col - DI] = f2b(v);
                } else {
                    C[o] = v;
                }
            }
        }
    }
}

// ---------------------------------------------------------------------------
// x_proj split-K MFMA: part[s][M][80] = xcb[M, s*192..+192] @ W[80, ...]^T
// grid (16 m-tiles, 8 k-chunks); wave owns 32 rows x 80 cols.
// ---------------------------------------------------------------------------
__global__ __launch_bounds__(256)
void xproj_mfma(const unsigned short* __restrict__ A,   // [2048][1536]
                const unsigned short* __restrict__ W,   // [80][1536]
                float* __restrict__ part)               // [8][2048][80]
{
    const int mt = blockIdx.x, s = blockIdx.y;
    const int lane = threadIdx.x & 63, wave = threadIdx.x >> 6;
    const int ln = lane & 15, lg = lane >> 4;
    const int row0 = mt * 128 + wave * 32;
    const int kb = s * 192;
    f32x4 acc[2][5];
    #pragma unroll
    for (int i = 0; i < 2; ++i)
        #pragma unroll
        for (int j = 0; j < 5; ++j)
            acc[i][j] = (f32x4){0.f, 0.f, 0.f, 0.f};

    for (int kk = 0; kk < 192; kk += 32) {
        const int k = kb + kk + lg * 8;
        bf16x8 af[2], wf[5];
        af[0] = *reinterpret_cast<const bf16x8*>(A + (size_t)(row0 + ln) * DI + k);
        af[1] = *reinterpret_cast<const bf16x8*>(A + (size_t)(row0 + 16 + ln) * DI + k);
        #pragma unroll
        for (int j = 0; j < 5; ++j)
            wf[j] = *reinterpret_cast<const bf16x8*>(W + (size_t)(j * 16 + ln) * DI + k);
        #pragma unroll
        for (int i = 0; i < 2; ++i)
            #pragma unroll
            for (int j = 0; j < 5; ++j)
                acc[i][j] = __builtin_amdgcn_mfma_f32_16x16x32_bf16(af[i], wf[j], acc[i][j], 0, 0, 0);
    }
    float* pb = part + (size_t)s * NROWS * 80;
    #pragma unroll
    for (int i = 0; i < 2; ++i)
        #pragma unroll
        for (int j = 0; j < 5; ++j)
            #pragma unroll
            for (int rr = 0; rr < 4; ++rr) {
                int row = row0 + i * 16 + lg * 4 + rr;
                int col = j * 16 + ln;
                pb[(size_t)row * 80 + col] = acc[i][j][rr];
            }
}

// Reduce split-K partials -> xdbl f32 [2048][80]; also emit bf16 dt-cols
// K-padded to 64 (cols 48..63 zero) for the dt_proj MFMA.
__global__ __launch_bounds__(256)
void xproj_reduce(const float* __restrict__ part, float* __restrict__ xdbl,
                  unsigned short* __restrict__ xdblb)
{
    int idx = blockIdx.x * 256 + threadIdx.x;      // 163840
    float sum = 0.f;
    #pragma unroll
    for (int s = 0; s < 8; ++s) sum += part[(size_t)s * NROWS * 80 + idx];
    xdbl[idx] = sum;
    int col = idx % 80, row = idx / 80;
    if (col < 48)      xdblb[row * 64 + col] = f2b(sum);
    else if (col < 64) xdblb[row * 64 + col] = 0;
}

// ---------------------------------------------------------------------------
// f32 -> bf16 conversion: x + 4 big weights + x_proj_w, one kernel.
// ---------------------------------------------------------------------------
__global__ __launch_bounds__(256)
void cvt6_k(const float* __restrict__ x,  const float* __restrict__ w1,
            const float* __restrict__ w2, const float* __restrict__ w3,
            const float* __restrict__ w4, const float* __restrict__ w5,
            unsigned short* __restrict__ xb,  unsigned short* __restrict__ w1b,
            unsigned short* __restrict__ w2b, unsigned short* __restrict__ w3b,
            unsigned short* __restrict__ w4b, unsigned short* __restrict__ w5b)
{
    size_t i4 = ((size_t)blockIdx.x * 256 + threadIdx.x) * 4;
    const float* src; unsigned short* dst; size_t off;
    if      (i4 < 1572864u) { src = x;  dst = xb;  off = i4; }
    else if (i4 < 3932160u) { src = w1; dst = w1b; off = i4 - 1572864u; }
    else if (i4 < 5111808u) { src = w2; dst = w2b; off = i4 - 3932160u; }
    else if (i4 < 7471104u) { src = w3; dst = w3b; off = i4 - 5111808u; }
    else if (i4 < 9830400u) { src = w4; dst = w4b; off = i4 - 7471104u; }
    else                    { src = w5; dst = w5b; off = i4 - 9830400u; }
    float4 v = *reinterpret_cast<const float4*>(src + off);
    ushort4 u;
    u.x = f2b(v.x); u.y = f2b(v.y); u.z = f2b(v.z); u.w = f2b(v.w);
    *reinterpret_cast<ushort4*>(dst + off) = u;
}

// dt_proj_w [1536][48] f32 -> bf16 padded to [1536][64]
__global__ __launch_bounds__(256)
void cvt_dtw(const float* __restrict__ w, unsigned short* __restrict__ wb)
{
    int idx = blockIdx.x * 256 + threadIdx.x;      // 98304
    int row = idx >> 6, col = idx & 63;
    wb[idx] = (col < 48) ? f2b(w[row * 48 + col]) : (unsigned short)0;
}

// ---------------------------------------------------------------------------
// Causal depthwise conv(4) + bias + SiLU; outputs f32 and bf16.
// ---------------------------------------------------------------------------
__global__ __launch_bounds__(256)
void conv_silu_k(const float* __restrict__ xin, const float* __restrict__ cw,
                 const float* __restrict__ cb, float* __restrict__ xc,
                 unsigned short* __restrict__ xcb)
{
    int idx = blockIdx.x * 256 + threadIdx.x;
    int d  = idx % DI;
    int bt = idx / DI;
    int t  = bt % SEQ, b = bt / SEQ;
    float w0 = cw[d*4], w1 = cw[d*4+1], w2 = cw[d*4+2], w3 = cw[d*4+3];
    const float* base = xin + ((size_t)b * SEQ) * DI + d;
    float acc = cb[d];
    if (t >= 3) acc += w0 * base[(size_t)(t - 3) * DI];
    if (t >= 2) acc += w1 * base[(size_t)(t - 2) * DI];
    if (t >= 1) acc += w2 * base[(size_t)(t - 1) * DI];
    acc += w3 * base[(size_t)t * DI];
    float v = acc / (1.f + expf(-acc));
    xc[idx] = v;
    xcb[idx] = f2b(v);
}

// ---------------------------------------------------------------------------
// Chunked SSM scan, phase A: per-chunk local scan from h0=0.
// ---------------------------------------------------------------------------
__global__ __launch_bounds__(256)
void scan_a(const float* __restrict__ delta, const float* __restrict__ xc,
            const float* __restrict__ xdbl,  const float* __restrict__ A_log,
            float* __restrict__ hfin, float* __restrict__ aprod)
{
    const int dblk = blockIdx.x, ch = blockIdx.y, b = blockIdx.z;
    const int d0 = dblk * 16, t0 = ch * TCH;
    __shared__ float del_s[TCH][17];
    __shared__ float xcs[TCH][17];
    __shared__ float b_s[TCH][16];
    const int tid = threadIdx.x;
    const int sr = tid >> 4, sc = tid & 15;
    for (int p = 0; p < 8; ++p) {
        int t = p * 16 + sr;
        size_t rowo = (size_t)(b * SEQ + t0 + t);
        del_s[t][sc] = delta[rowo * DI + d0 + sc];
        xcs[t][sc]   = xc[rowo * DI + d0 + sc];
        b_s[t][sc]   = xdbl[rowo * 80 + DTRANK + sc];
    }
    __syncthreads();
    const int lane = tid & 63, wave = tid >> 6;
    const int wd = wave * 4 + (lane >> 4), n = lane & 15;
    const int d = d0 + wd;
    const float Adn = -expf(A_log[d * DSTATE + n]);
    float h = 0.f, ap = 1.f;
    for (int t = 0; t < TCH; ++t) {
        float dl = del_s[t][wd];
        float dA = expf(dl * Adn);
        h = dA * h + dl * b_s[t][n] * xcs[t][wd];
        ap *= dA;
    }
    size_t o = ((size_t)(b * NCH + ch) * DI + d) * DSTATE + n;
    hfin[o] = h; aprod[o] = ap;
}

// ---------------------------------------------------------------------------
// Phase C: recombine chunk prefixes, rerun, gated bf16 y.
// ---------------------------------------------------------------------------
__global__ __launch_bounds__(256)
void scan_c(const float* __restrict__ delta, const float* __restrict__ xc,
            const float* __restrict__ xdbl,  const float* __restrict__ A_log,
            const float* __restrict__ Dp,    const unsigned short* __restrict__ zb,
            const float* __restrict__ hfin,  const float* __restrict__ aprod,
            unsigned short* __restrict__ yb)
{
    const int dblk = blockIdx.x, ch = blockIdx.y, b = blockIdx.z;
    const int d0 = dblk * 16, t0 = ch * TCH;
    __shared__ float del_s[TCH][17];
    __shared__ float xcs[TCH][17];
    __shared__ float b_s[TCH][16];
    __shared__ float c_s[TCH][16];
    __shared__ float z_s[TCH][17];
    __shared__ unsigned short y_s[TCH][16];
    const int tid = threadIdx.x;
    const int sr = tid >> 4, sc = tid & 15;
    for (int p = 0; p < 8; ++p) {
        int t = p * 16 + sr;
        size_t rowo = (size_t)(b * SEQ + t0 + t);
        del_s[t][sc] = delta[rowo * DI + d0 + sc];
        xcs[t][sc]   = xc[rowo * DI + d0 + sc];
        b_s[t][sc]   = xdbl[rowo * 80 + DTRANK + sc];
        c_s[t][sc]   = xdbl[rowo * 80 + DTRANK + DSTATE + sc];
        z_s[t][sc]   = b2f(zb[rowo * DI + d0 + sc]);
    }
    __syncthreads();
    const int lane = tid & 63, wave = tid >> 6;
    const int wd = wave * 4 + (lane >> 4), n = lane & 15;
    const int d = d0 + wd;
    const float Adn = -expf(A_log[d * DSTATE + n]);
    const float Dd = Dp[d];
    float h = 0.f;
    for (int cc = 0; cc < ch; ++cc) {
        size_t o = ((size_t)(b * NCH + cc) * DI + d) * DSTATE + n;
        h = aprod[o] * h + hfin[o];
    }
    for (int t = 0; t < TCH; ++t) {
        float dl = del_s[t][wd], xv = xcs[t][wd];
        float dA = expf(dl * Adn);
        h = dA * h + dl * b_s[t][n] * xv;
        float py = h * c_s[t][n];
        py += __shfl_xor(py, 1);
        py += __shfl_xor(py, 2);
        py += __shfl_xor(py, 4);
        py += __shfl_xor(py, 8);
        if (n == 0) {
            float yv = py + xv * Dd;
            float zv = z_s[t][wd];
            y_s[t][wd] = f2b(yv * zv / (1.f + expf(-zv)));
        }
    }
    __syncthreads();
    for (int p = 0; p < 8; ++p) {
        int t = p * 16 + sr;
        yb[(size_t)(b * SEQ + t0 + t) * DI + d0 + sc] = y_s[t][sc];
    }
}

// ---------------------------------------------------------------------------
// LayerNorm over 768, optional bf16 secondary output.
// ---------------------------------------------------------------------------
__global__ __launch_bounds__(256)
void layernorm_k(const float* __restrict__ in, const float* __restrict__ w,
                 const float* __restrict__ bb, float* __restrict__ out,
                 unsigned short* __restrict__ outb)
{
    const int row = blockIdx.x;
    const float* xr = in + (size_t)row * EMBED;
    const int i0 = threadIdx.x, i1 = i0 + 256, i2 = i0 + 512;
    float v0 = xr[i0], v1 = xr[i1], v2 = xr[i2];
    float s  = v0 + v1 + v2;
    float s2 = v0 * v0 + v1 * v1 + v2 * v2;
    #pragma unroll
    for (int m = 1; m < 64; m <<= 1) {
        s  += __shfl_xor(s,  m);
        s2 += __shfl_xor(s2, m);
    }
    __shared__ float sh1[4], sh2[4];
    int wv = threadIdx.x >> 6;
    if ((threadIdx.x & 63) == 0) { sh1[wv] = s; sh2[wv] = s2; }
    __syncthreads();
    float S1 = sh1[0] + sh1[1] + sh1[2] + sh1[3];
    float S2 = sh2[0] + sh2[1] + sh2[2] + sh2[3];
    float mu  = S1 * (1.f / EMBED);
    float var = S2 * (1.f / EMBED) - mu * mu;
    float rs  = rsqrtf(var + 1e-5f);
    float* orow = out + (size_t)row * EMBED;
    float o0 = (v0 - mu) * rs * w[i0] + bb[i0];
    float o1 = (v1 - mu) * rs * w[i1] + bb[i1];
    float o2 = (v2 - mu) * rs * w[i2] + bb[i2];
    orow[i0] = o0; orow[i1] = o1; orow[i2] = o2;
    if (outb) {
        unsigned short* obr = outb + (size_t)row * EMBED;
        obr[i0] = f2b(o0); obr[i1] = f2b(o1); obr[i2] = f2b(o2);
    }
}

// ---------------------------------------------------------------------------
extern "C" void kernel_launch(void* const* d_in, const int* in_sizes, int n_in,
                              void* d_out, int out_size, void* d_ws, size_t ws_size,
                              hipStream_t stream)
{
    const float* x         = (const float*)d_in[0];
    const float* in_proj_w = (const float*)d_in[1];
    const float* conv_w    = (const float*)d_in[2];
    const float* conv_b    = (const float*)d_in[3];
    const float* x_proj_w  = (const float*)d_in[4];
    const float* dt_proj_w = (const float*)d_in[5];
    const float* dt_proj_b = (const float*)d_in[6];
    const float* A_log     = (const float*)d_in[7];
    const float* D_param   = (const float*)d_in[8];
    const float* out_proj_w= (const float*)d_in[9];
    const float* ln1_w     = (const float*)d_in[10];
    const float* ln1_b     = (const float*)d_in[11];
    const float* ln2_w     = (const float*)d_in[12];
    const float* ln2_b     = (const float*)d_in[13];
    const float* ffn_w1    = (const float*)d_in[14];
    const float* ffn_b1    = (const float*)d_in[15];
    const float* ffn_w2    = (const float*)d_in[16];
    const float* ffn_b2    = (const float*)d_in[17];
    float* out = (float*)d_out;

    char* Wp = (char*)d_ws;
    float*          xin   = (float*)         (Wp + 0);          // 12582912, dead after conv
    unsigned short* zbuf  = (unsigned short*)(Wp + 12582912);   // 6291456
    float*          xc    = (float*)         (Wp + 18874368);   // 12582912
    float*          xdbl  = (float*)         (Wp + 31457280);   // 655360
    float*          delta = (float*)         (Wp + 32112640);   // 12582912
    unsigned short* ybb   = (unsigned short*)(Wp + 44695552);   // 6291456
    float*          hres  = (float*)         (Wp + 50987008);   // 6291456, written step 8
    float*          hfin  = (float*)         (Wp + 57278464);   // 786432
    float*          aprod = (float*)         (Wp + 58064896);   // 786432
    unsigned short* xb    = (unsigned short*)(Wp + 58851328);   // 3145728, dead after in_proj
    unsigned short* wib   = (unsigned short*)(Wp + 61997056);   // 4718592, dead after in_proj
    unsigned short* wob   = (unsigned short*)(Wp + 66715648);   // 2359296
    unsigned short* wf1b  = (unsigned short*)(Wp + 69074944);   // 4718592
    unsigned short* wf2b  = (unsigned short*)(Wp + 73793536);   // 4718592
    // aliases into dead regions:
    unsigned short* fbf   = (unsigned short*)(Wp + 0);          // ffn1 out (step 10)
    float*          ores  = (float*)         (Wp + 12582912);   // ffn2 out (step 11)
    float*          x1    = (float*)         (Wp + 32112640);   // LN1 out (step 9)
    unsigned short* x1b   = (unsigned short*)(Wp + 58851328);   // LN1 bf16 (step 9)
    float*          part  = (float*)         (Wp + 0);          // [8][2048][80], steps 4a-4b (xin dead)
    unsigned short* xdblb = (unsigned short*)(Wp + 5242880);    // [2048][64], steps 4b-5 (xin dead)
    unsigned short* xcb   = (unsigned short*)(Wp + 58851328);   // conv bf16 out, steps 3-4a (xb/wib dead)
    unsigned short* xpwb  = (unsigned short*)(Wp + 50987008);   // x_proj_w bf16, steps 1-4a (hres not yet written)
    unsigned short* wdtb  = (unsigned short*)(Wp + 51232768);   // dt_proj_w bf16 padded, steps 1-5

    dim3 blk(256);

    // 1. bf16 conversions
    cvt6_k<<<9720, blk, 0, stream>>>(x, in_proj_w, out_proj_w, ffn_w1, ffn_w2, x_proj_w,
                                     xb, wib, wob, wf1b, wf2b, xpwb);
    cvt_dtw<<<384, blk, 0, stream>>>(dt_proj_w, wdtb);

    // 2. in_proj (MFMA, split epilogue): xin f32 + z bf16
    gemm_mfma<5><<<dim3(24, 16), blk, 0, stream>>>(xb, wib, xin, zbuf,
                                                   NROWS, 2 * DI, EMBED, nullptr, nullptr);

    // 3. conv + silu -> xc f32 + xcb bf16
    conv_silu_k<<<(BATCH * SEQ * DI) / 256, blk, 0, stream>>>(xin, conv_w, conv_b, xc, xcb);

    // 4. x_proj split-K MFMA + reduce -> xdbl f32, xdblb bf16(pad64)
    xproj_mfma<<<dim3(16, 8), blk, 0, stream>>>(xcb, xpwb, part);
    xproj_reduce<<<640, blk, 0, stream>>>(part, xdbl, xdblb);

    // 5. dt_proj (MFMA) + softplus -> delta f32
    gemm_mfma<1><<<dim3(12, 16), blk, 0, stream>>>(xdblb, wdtb, delta, nullptr,
                                                   NROWS, DI, 64, dt_proj_b, nullptr);

    // 6-7. chunked scan
    scan_a<<<dim3(96, NCH, BATCH), blk, 0, stream>>>(delta, xc, xdbl, A_log, hfin, aprod);
    scan_c<<<dim3(96, NCH, BATCH), blk, 0, stream>>>(delta, xc, xdbl, A_log, D_param, zbuf,
                                                     hfin, aprod, ybb);

    // 8. out_proj (MFMA) + resid x -> hres f32
    gemm_mfma<2><<<dim3(6, 16), blk, 0, stream>>>(ybb, wob, hres, nullptr,
                                                  NROWS, EMBED, DI, nullptr, x);

    // 9. LN1 -> x1 f32 + x1b bf16
    layernorm_k<<<NROWS, blk, 0, stream>>>(hres, ln1_w, ln1_b, x1, x1b);

    // 10. ffn1 (MFMA) + gelu -> fbf bf16
    gemm_mfma<3><<<dim3(24, 16), blk, 0, stream>>>(x1b, wf1b, nullptr, fbf,
                                                   NROWS, FF, EMBED, ffn_b1, nullptr);

    // 11. ffn2 (MFMA) + bias + resid x1 -> ores f32
    gemm_mfma<4><<<dim3(6, 16), blk, 0, stream>>>(fbf, wf2b, ores, nullptr,
                                                  NROWS, EMBED, FF, ffn_b2, x1);

    // 12. LN2 -> out
    layernorm_k<<<NROWS, blk, 0, stream>>>(ores, ln2_w, ln2_b, out, nullptr);
}

// Round 4
// 322.381 us; speedup vs baseline: 6.0487x; 1.1479x over previous
//
#include <hip/hip_runtime.h>
#include <math.h>

#define EMBED 768
#define DI 1536
#define DSTATE 16
#define DCONV 4
#define DTRANK 48
#define FF 3072
#define BATCH 2
#define SEQ 1024
#define NROWS (BATCH*SEQ)
#define TCH 64
#define NCH (SEQ/TCH)

typedef __bf16 bf16x8 __attribute__((ext_vector_type(8)));
typedef float f32x4 __attribute__((ext_vector_type(4)));
typedef unsigned int u32x4 __attribute__((ext_vector_type(4)));

static __device__ __forceinline__ unsigned short f2b(float f) {
    union { float f; unsigned u; } v; v.f = f;
    unsigned r = v.u + 0x7FFFu + ((v.u >> 16) & 1u);
    return (unsigned short)(r >> 16);
}
static __device__ __forceinline__ float b2f(unsigned short s) {
    union { unsigned u; float f; } v; v.u = ((unsigned)s) << 16;
    return v.f;
}

// ---------------------------------------------------------------------------
// bf16 MFMA GEMM: C[M,N] = A[M,K](bf16) @ W[N,K](bf16)^T, f32 accum.
// 128x128 tile, BK=32, 4 waves each owning 64x64 (4x4 frags of 16x16x32).
// EPI: 1 softplus(acc+bias)->C ; 2 +resid(f32)->C ; 3 gelu(acc+bias)->Cb ;
//      4 +bias+resid->C ; 5 split: col<DI -> C(f32), col>=DI -> Cb(bf16)
// ---------------------------------------------------------------------------
template<int EPI>
__global__ __launch_bounds__(256)
void gemm_mfma(const unsigned short* __restrict__ A,
               const unsigned short* __restrict__ W,
               float* __restrict__ C, unsigned short* __restrict__ Cb,
               int M, int N, int K,
               const float* __restrict__ bias,
               const float* __restrict__ resid)
{
    __shared__ alignas(16) unsigned short As[128 * 40];
    __shared__ alignas(16) unsigned short Ws[128 * 40];
    const int tid  = threadIdx.x;
    const int lane = tid & 63, wave = tid >> 6;
    const int wr = (wave >> 1) * 64, wc = (wave & 1) * 64;
    const int bm = blockIdx.y * 128, bn = blockIdx.x * 128;
    const int ln = lane & 15, lg = lane >> 4;
    const int r = tid >> 2, cg = tid & 3;

    f32x4 acc[4][4];
    #pragma unroll
    for (int i = 0; i < 4; ++i)
        #pragma unroll
        for (int j = 0; j < 4; ++j)
            acc[i][j] = (f32x4){0.f, 0.f, 0.f, 0.f};

    const unsigned short* gA0 = A + (size_t)(bm + r) * K + cg * 8;
    const unsigned short* gA1 = A + (size_t)(bm + r + 64) * K + cg * 8;
    const unsigned short* gW0 = W + (size_t)(bn + r) * K + cg * 8;
    const unsigned short* gW1 = W + (size_t)(bn + r + 64) * K + cg * 8;

    for (int k0 = 0; k0 < K; k0 += 32) {
        u32x4 a0 = *reinterpret_cast<const u32x4*>(gA0 + k0);
        u32x4 a1 = *reinterpret_cast<const u32x4*>(gA1 + k0);
        u32x4 w0 = *reinterpret_cast<const u32x4*>(gW0 + k0);
        u32x4 w1 = *reinterpret_cast<const u32x4*>(gW1 + k0);
        __syncthreads();
        *reinterpret_cast<u32x4*>(&As[r * 40 + cg * 8]) = a0;
        *reinterpret_cast<u32x4*>(&As[(r + 64) * 40 + cg * 8]) = a1;
        *reinterpret_cast<u32x4*>(&Ws[r * 40 + cg * 8]) = w0;
        *reinterpret_cast<u32x4*>(&Ws[(r + 64) * 40 + cg * 8]) = w1;
        __syncthreads();
        bf16x8 af[4], wf[4];
        #pragma unroll
        for (int i = 0; i < 4; ++i)
            af[i] = *reinterpret_cast<const bf16x8*>(&As[(wr + i * 16 + ln) * 40 + lg * 8]);
        #pragma unroll
        for (int j = 0; j < 4; ++j)
            wf[j] = *reinterpret_cast<const bf16x8*>(&Ws[(wc + j * 16 + ln) * 40 + lg * 8]);
        #pragma unroll
        for (int i = 0; i < 4; ++i)
            #pragma unroll
            for (int j = 0; j < 4; ++j)
                acc[i][j] = __builtin_amdgcn_mfma_f32_16x16x32_bf16(af[i], wf[j], acc[i][j], 0, 0, 0);
    }

    #pragma unroll
    for (int i = 0; i < 4; ++i) {
        #pragma unroll
        for (int j = 0; j < 4; ++j) {
            int col = bn + wc + j * 16 + ln;
            #pragma unroll
            for (int rr = 0; rr < 4; ++rr) {
                int row = bm + wr + i * 16 + lg * 4 + rr;
                float v = acc[i][j][rr];
                size_t o = (size_t)row * N + col;
                if (EPI == 1) {
                    v += bias[col];
                    C[o] = (v > 20.f) ? v : log1pf(expf(v));
                } else if (EPI == 2) {
                    C[o] = v + resid[o];
                } else if (EPI == 3) {
                    v += bias[col];
                    float t = 0.7978845608028654f * (v + 0.044715f * v * v * v);
                    Cb[o] = f2b(0.5f * v * (1.f + tanhf(t)));
                } else if (EPI == 4) {
                    C[o] = v + bias[col] + resid[o];
                } else if (EPI == 5) {
                    if (col < DI) C[(size_t)row * DI + col] = v;
                    else          Cb[(size_t)row * DI + col - DI] = f2b(v);
                } else {
                    C[o] = v;
                }
            }
        }
    }
}

// ---------------------------------------------------------------------------
// x_proj split-K MFMA: part[s][M][80] = xcb[M, s*192..+192] @ W[80, ...]^T
// ---------------------------------------------------------------------------
__global__ __launch_bounds__(256)
void xproj_mfma(const unsigned short* __restrict__ A,
                const unsigned short* __restrict__ W,
                float* __restrict__ part)
{
    const int mt = blockIdx.x, s = blockIdx.y;
    const int lane = threadIdx.x & 63, wave = threadIdx.x >> 6;
    const int ln = lane & 15, lg = lane >> 4;
    const int row0 = mt * 128 + wave * 32;
    const int kb = s * 192;
    f32x4 acc[2][5];
    #pragma unroll
    for (int i = 0; i < 2; ++i)
        #pragma unroll
        for (int j = 0; j < 5; ++j)
            acc[i][j] = (f32x4){0.f, 0.f, 0.f, 0.f};

    for (int kk = 0; kk < 192; kk += 32) {
        const int k = kb + kk + lg * 8;
        bf16x8 af[2], wf[5];
        af[0] = *reinterpret_cast<const bf16x8*>(A + (size_t)(row0 + ln) * DI + k);
        af[1] = *reinterpret_cast<const bf16x8*>(A + (size_t)(row0 + 16 + ln) * DI + k);
        #pragma unroll
        for (int j = 0; j < 5; ++j)
            wf[j] = *reinterpret_cast<const bf16x8*>(W + (size_t)(j * 16 + ln) * DI + k);
        #pragma unroll
        for (int i = 0; i < 2; ++i)
            #pragma unroll
            for (int j = 0; j < 5; ++j)
                acc[i][j] = __builtin_amdgcn_mfma_f32_16x16x32_bf16(af[i], wf[j], acc[i][j], 0, 0, 0);
    }
    float* pb = part + (size_t)s * NROWS * 80;
    #pragma unroll
    for (int i = 0; i < 2; ++i)
        #pragma unroll
        for (int j = 0; j < 5; ++j)
            #pragma unroll
            for (int rr = 0; rr < 4; ++rr) {
                int row = row0 + i * 16 + lg * 4 + rr;
                int col = j * 16 + ln;
                pb[(size_t)row * 80 + col] = acc[i][j][rr];
            }
}

__global__ __launch_bounds__(256)
void xproj_reduce(const float* __restrict__ part, float* __restrict__ xdbl,
                  unsigned short* __restrict__ xdblb)
{
    int idx = blockIdx.x * 256 + threadIdx.x;      // 163840
    float sum = 0.f;
    #pragma unroll
    for (int s = 0; s < 8; ++s) sum += part[(size_t)s * NROWS * 80 + idx];
    xdbl[idx] = sum;
    int col = idx % 80, row = idx / 80;
    if (col < 48)      xdblb[row * 64 + col] = f2b(sum);
    else if (col < 64) xdblb[row * 64 + col] = 0;
}

// ---------------------------------------------------------------------------
// f32 -> bf16 conversions
// ---------------------------------------------------------------------------
__global__ __launch_bounds__(256)
void cvt6_k(const float* __restrict__ x,  const float* __restrict__ w1,
            const float* __restrict__ w2, const float* __restrict__ w3,
            const float* __restrict__ w4, const float* __restrict__ w5,
            unsigned short* __restrict__ xb,  unsigned short* __restrict__ w1b,
            unsigned short* __restrict__ w2b, unsigned short* __restrict__ w3b,
            unsigned short* __restrict__ w4b, unsigned short* __restrict__ w5b)
{
    size_t i4 = ((size_t)blockIdx.x * 256 + threadIdx.x) * 4;
    const float* src; unsigned short* dst; size_t off;
    if      (i4 < 1572864u) { src = x;  dst = xb;  off = i4; }
    else if (i4 < 3932160u) { src = w1; dst = w1b; off = i4 - 1572864u; }
    else if (i4 < 5111808u) { src = w2; dst = w2b; off = i4 - 3932160u; }
    else if (i4 < 7471104u) { src = w3; dst = w3b; off = i4 - 5111808u; }
    else if (i4 < 9830400u) { src = w4; dst = w4b; off = i4 - 7471104u; }
    else                    { src = w5; dst = w5b; off = i4 - 9830400u; }
    float4 v = *reinterpret_cast<const float4*>(src + off);
    ushort4 u;
    u.x = f2b(v.x); u.y = f2b(v.y); u.z = f2b(v.z); u.w = f2b(v.w);
    *reinterpret_cast<ushort4*>(dst + off) = u;
}

__global__ __launch_bounds__(256)
void cvt_dtw(const float* __restrict__ w, unsigned short* __restrict__ wb)
{
    int idx = blockIdx.x * 256 + threadIdx.x;      // 98304
    int row = idx >> 6, col = idx & 63;
    wb[idx] = (col < 48) ? f2b(w[row * 48 + col]) : (unsigned short)0;
}

// ---------------------------------------------------------------------------
// Causal depthwise conv(4) + bias + SiLU (native exp).
// ---------------------------------------------------------------------------
__global__ __launch_bounds__(256)
void conv_silu_k(const float* __restrict__ xin, const float* __restrict__ cw,
                 const float* __restrict__ cb, float* __restrict__ xc,
                 unsigned short* __restrict__ xcb)
{
    int idx = blockIdx.x * 256 + threadIdx.x;
    int d  = idx % DI;
    int bt = idx / DI;
    int t  = bt % SEQ, b = bt / SEQ;
    float w0 = cw[d*4], w1 = cw[d*4+1], w2 = cw[d*4+2], w3 = cw[d*4+3];
    const float* base = xin + ((size_t)b * SEQ) * DI + d;
    float acc = cb[d];
    if (t >= 3) acc += w0 * base[(size_t)(t - 3) * DI];
    if (t >= 2) acc += w1 * base[(size_t)(t - 2) * DI];
    if (t >= 1) acc += w2 * base[(size_t)(t - 1) * DI];
    acc += w3 * base[(size_t)t * DI];
    float v = acc / (1.f + __expf(-acc));
    xc[idx] = v;
    xcb[idx] = f2b(v);
}

// ---------------------------------------------------------------------------
// Chunked SSM scan, phase A: per-chunk local scan from h0=0 (TCH=64).
// ---------------------------------------------------------------------------
__global__ __launch_bounds__(256)
void scan_a(const float* __restrict__ delta, const float* __restrict__ xc,
            const float* __restrict__ xdbl,  const float* __restrict__ A_log,
            float* __restrict__ hfin, float* __restrict__ aprod)
{
    const int dblk = blockIdx.x, ch = blockIdx.y, b = blockIdx.z;
    const int d0 = dblk * 16, t0 = ch * TCH;
    __shared__ float del_s[TCH][17];
    __shared__ float xcs[TCH][17];
    __shared__ float b_s[TCH][16];
    const int tid = threadIdx.x;
    const int sr = tid >> 4, sc = tid & 15;
    #pragma unroll
    for (int p = 0; p < 4; ++p) {
        int t = p * 16 + sr;
        size_t rowo = (size_t)(b * SEQ + t0 + t);
        del_s[t][sc] = delta[rowo * DI + d0 + sc];
        xcs[t][sc]   = xc[rowo * DI + d0 + sc];
        b_s[t][sc]   = xdbl[rowo * 80 + DTRANK + sc];
    }
    __syncthreads();
    const int lane = tid & 63, wave = tid >> 6;
    const int wd = wave * 4 + (lane >> 4), n = lane & 15;
    const int d = d0 + wd;
    const float Adn = -__expf(A_log[d * DSTATE + n]);
    float h = 0.f, ap = 1.f;
    #pragma unroll 4
    for (int t = 0; t < TCH; ++t) {
        float dl = del_s[t][wd];
        float dA = __expf(dl * Adn);
        h = dA * h + dl * b_s[t][n] * xcs[t][wd];
        ap *= dA;
    }
    size_t o = ((size_t)(b * NCH + ch) * DI + d) * DSTATE + n;
    hfin[o] = h; aprod[o] = ap;
}

// ---------------------------------------------------------------------------
// Phase B: per-(b,d,n) serial combine over the 16 chunks -> h0 per chunk.
// ---------------------------------------------------------------------------
__global__ __launch_bounds__(256)
void scan_b(const float* __restrict__ hfin, const float* __restrict__ aprod,
            float* __restrict__ h0)
{
    int idx = blockIdx.x * 256 + threadIdx.x;      // B*DI*16 = 49152
    int n = idx & 15;
    int d = (idx >> 4) % DI;
    int b = idx / (DI * DSTATE);
    float h = 0.f;
    #pragma unroll
    for (int ch = 0; ch < NCH; ++ch) {
        size_t o = ((size_t)(b * NCH + ch) * DI + d) * DSTATE + n;
        h0[o] = h;
        h = aprod[o] * h + hfin[o];
    }
}

// ---------------------------------------------------------------------------
// Phase C: start from h0, run chunk, produce gated bf16 y.
// ---------------------------------------------------------------------------
__global__ __launch_bounds__(256)
void scan_c(const float* __restrict__ delta, const float* __restrict__ xc,
            const float* __restrict__ xdbl,  const float* __restrict__ A_log,
            const float* __restrict__ Dp,    const unsigned short* __restrict__ zb,
            const float* __restrict__ h0,
            unsigned short* __restrict__ yb)
{
    const int dblk = blockIdx.x, ch = blockIdx.y, b = blockIdx.z;
    const int d0 = dblk * 16, t0 = ch * TCH;
    __shared__ float del_s[TCH][17];
    __shared__ float xcs[TCH][17];
    __shared__ float b_s[TCH][16];
    __shared__ float c_s[TCH][16];
    __shared__ float z_s[TCH][17];
    __shared__ unsigned short y_s[TCH][16];
    const int tid = threadIdx.x;
    const int sr = tid >> 4, sc = tid & 15;
    #pragma unroll
    for (int p = 0; p < 4; ++p) {
        int t = p * 16 + sr;
        size_t rowo = (size_t)(b * SEQ + t0 + t);
        del_s[t][sc] = delta[rowo * DI + d0 + sc];
        xcs[t][sc]   = xc[rowo * DI + d0 + sc];
        b_s[t][sc]   = xdbl[rowo * 80 + DTRANK + sc];
        c_s[t][sc]   = xdbl[rowo * 80 + DTRANK + DSTATE + sc];
        z_s[t][sc]   = b2f(zb[rowo * DI + d0 + sc]);
    }
    __syncthreads();
    const int lane = tid & 63, wave = tid >> 6;
    const int wd = wave * 4 + (lane >> 4), n = lane & 15;
    const int d = d0 + wd;
    const float Adn = -__expf(A_log[d * DSTATE + n]);
    const float Dd = Dp[d];
    float h = h0[((size_t)(b * NCH + ch) * DI + d) * DSTATE + n];
    #pragma unroll 4
    for (int t = 0; t < TCH; ++t) {
        float dl = del_s[t][wd], xv = xcs[t][wd];
        float dA = __expf(dl * Adn);
        h = dA * h + dl * b_s[t][n] * xv;
        float py = h * c_s[t][n];
        py += __shfl_xor(py, 1);
        py += __shfl_xor(py, 2);
        py += __shfl_xor(py, 4);
        py += __shfl_xor(py, 8);
        if (n == 0) {
            float yv = py + xv * Dd;
            float zv = z_s[t][wd];
            y_s[t][wd] = f2b(yv * zv / (1.f + __expf(-zv)));
        }
    }
    __syncthreads();
    #pragma unroll
    for (int p = 0; p < 4; ++p) {
        int t = p * 16 + sr;
        yb[(size_t)(b * SEQ + t0 + t) * DI + d0 + sc] = y_s[t][sc];
    }
}

// ---------------------------------------------------------------------------
// LayerNorm over 768, optional bf16 secondary output.
// ---------------------------------------------------------------------------
__global__ __launch_bounds__(256)
void layernorm_k(const float* __restrict__ in, const float* __restrict__ w,
                 const float* __restrict__ bb, float* __restrict__ out,
                 unsigned short* __restrict__ outb)
{
    const int row = blockIdx.x;
    const float* xr = in + (size_t)row * EMBED;
    const int i0 = threadIdx.x, i1 = i0 + 256, i2 = i0 + 512;
    float v0 = xr[i0], v1 = xr[i1], v2 = xr[i2];
    float s  = v0 + v1 + v2;
    float s2 = v0 * v0 + v1 * v1 + v2 * v2;
    #pragma unroll
    for (int m = 1; m < 64; m <<= 1) {
        s  += __shfl_xor(s,  m);
        s2 += __shfl_xor(s2, m);
    }
    __shared__ float sh1[4], sh2[4];
    int wv = threadIdx.x >> 6;
    if ((threadIdx.x & 63) == 0) { sh1[wv] = s; sh2[wv] = s2; }
    __syncthreads();
    float S1 = sh1[0] + sh1[1] + sh1[2] + sh1[3];
    float S2 = sh2[0] + sh2[1] + sh2[2] + sh2[3];
    float mu  = S1 * (1.f / EMBED);
    float var = S2 * (1.f / EMBED) - mu * mu;
    float rs  = rsqrtf(var + 1e-5f);
    float* orow = out + (size_t)row * EMBED;
    float o0 = (v0 - mu) * rs * w[i0] + bb[i0];
    float o1 = (v1 - mu) * rs * w[i1] + bb[i1];
    float o2 = (v2 - mu) * rs * w[i2] + bb[i2];
    orow[i0] = o0; orow[i1] = o1; orow[i2] = o2;
    if (outb) {
        unsigned short* obr = outb + (size_t)row * EMBED;
        obr[i0] = f2b(o0); obr[i1] = f2b(o1); obr[i2] = f2b(o2);
    }
}

// ---------------------------------------------------------------------------
extern "C" void kernel_launch(void* const* d_in, const int* in_sizes, int n_in,
                              void* d_out, int out_size, void* d_ws, size_t ws_size,
                              hipStream_t stream)
{
    const float* x         = (const float*)d_in[0];
    const float* in_proj_w = (const float*)d_in[1];
    const float* conv_w    = (const float*)d_in[2];
    const float* conv_b    = (const float*)d_in[3];
    const float* x_proj_w  = (const float*)d_in[4];
    const float* dt_proj_w = (const float*)d_in[5];
    const float* dt_proj_b = (const float*)d_in[6];
    const float* A_log     = (const float*)d_in[7];
    const float* D_param   = (const float*)d_in[8];
    const float* out_proj_w= (const float*)d_in[9];
    const float* ln1_w     = (const float*)d_in[10];
    const float* ln1_b     = (const float*)d_in[11];
    const float* ln2_w     = (const float*)d_in[12];
    const float* ln2_b     = (const float*)d_in[13];
    const float* ffn_w1    = (const float*)d_in[14];
    const float* ffn_b1    = (const float*)d_in[15];
    const float* ffn_w2    = (const float*)d_in[16];
    const float* ffn_b2    = (const float*)d_in[17];
    float* out = (float*)d_out;

    char* Wp = (char*)d_ws;
    // static regions (lifetimes in step numbers)
    float*          xin   = (float*)         (Wp + 0);          // [2-3]
    unsigned short* zbuf  = (unsigned short*)(Wp + 12582912);   // [2-7]
    float*          xc    = (float*)         (Wp + 18874368);   // [3-7]
    float*          xdbl  = (float*)         (Wp + 31457280);   // [4b-7]
    float*          delta = (float*)         (Wp + 32112640);   // [5-7]
    unsigned short* ybb   = (unsigned short*)(Wp + 44695552);   // [7-8]
    float*          hres  = (float*)         (Wp + 50987008);   // [8-9]
    unsigned short* xb    = (unsigned short*)(Wp + 58851328);   // [1-2]
    unsigned short* wib   = (unsigned short*)(Wp + 61997056);   // [1-2]
    unsigned short* wob   = (unsigned short*)(Wp + 66715648);   // [1-8]
    unsigned short* wf1b  = (unsigned short*)(Wp + 69074944);   // [1-10]
    unsigned short* wf2b  = (unsigned short*)(Wp + 73793536);   // [1-11]
    // aliases into dead regions:
    unsigned short* fbf   = (unsigned short*)(Wp + 0);          // [10-11] (xin dead)
    float*          ores  = (float*)         (Wp + 12582912);   // [11-12] (zbuf dead)
    float*          x1    = (float*)         (Wp + 32112640);   // [9-12]  (delta dead)
    unsigned short* x1b   = (unsigned short*)(Wp + 58851328);   // [9-10]  (xb dead)
    float*          part  = (float*)         (Wp + 0);          // [4a-4b] (xin dead)
    unsigned short* xdblb = (unsigned short*)(Wp + 5242880);    // [4b-5]  (xin dead)
    unsigned short* xcb   = (unsigned short*)(Wp + 58851328);   // [3-4a]  (xb/wib dead)
    unsigned short* xpwb  = (unsigned short*)(Wp + 50987008);   // [1-4a]  (hres later)
    unsigned short* wdtb  = (unsigned short*)(Wp + 51232768);   // [1-5]   (hres later)
    float*          hfin  = (float*)         (Wp + 57278464);   // [6-6b]  3.1MB (xcb dead)
    float*          aprod = (float*)         (Wp + 60424192);   // [6-6b]  3.1MB
    float*          h0    = (float*)         (Wp + 63569920);   // [6b-7]  3.1MB, ends at wob

    dim3 blk(256);

    // 1. bf16 conversions
    cvt6_k<<<9720, blk, 0, stream>>>(x, in_proj_w, out_proj_w, ffn_w1, ffn_w2, x_proj_w,
                                     xb, wib, wob, wf1b, wf2b, xpwb);
    cvt_dtw<<<384, blk, 0, stream>>>(dt_proj_w, wdtb);

    // 2. in_proj (MFMA, split epilogue): xin f32 + z bf16
    gemm_mfma<5><<<dim3(24, 16), blk, 0, stream>>>(xb, wib, xin, zbuf,
                                                   NROWS, 2 * DI, EMBED, nullptr, nullptr);

    // 3. conv + silu -> xc f32 + xcb bf16
    conv_silu_k<<<(BATCH * SEQ * DI) / 256, blk, 0, stream>>>(xin, conv_w, conv_b, xc, xcb);

    // 4. x_proj split-K MFMA + reduce
    xproj_mfma<<<dim3(16, 8), blk, 0, stream>>>(xcb, xpwb, part);
    xproj_reduce<<<640, blk, 0, stream>>>(part, xdbl, xdblb);

    // 5. dt_proj (MFMA) + softplus -> delta f32
    gemm_mfma<1><<<dim3(12, 16), blk, 0, stream>>>(xdblb, wdtb, delta, nullptr,
                                                   NROWS, DI, 64, dt_proj_b, nullptr);

    // 6. chunked scan: local scans, prefix combine, finish
    scan_a<<<dim3(96, NCH, BATCH), blk, 0, stream>>>(delta, xc, xdbl, A_log, hfin, aprod);
    scan_b<<<192, blk, 0, stream>>>(hfin, aprod, h0);
    scan_c<<<dim3(96, NCH, BATCH), blk, 0, stream>>>(delta, xc, xdbl, A_log, D_param, zbuf,
                                                     h0, ybb);

    // 8. out_proj (MFMA) + resid x -> hres f32
    gemm_mfma<2><<<dim3(6, 16), blk, 0, stream>>>(ybb, wob, hres, nullptr,
                                                  NROWS, EMBED, DI, nullptr, x);

    // 9. LN1 -> x1 f32 + x1b bf16
    layernorm_k<<<NROWS, blk, 0, stream>>>(hres, ln1_w, ln1_b, x1, x1b);

    // 10. ffn1 (MFMA) + gelu -> fbf bf16
    gemm_mfma<3><<<dim3(24, 16), blk, 0, stream>>>(x1b, wf1b, nullptr, fbf,
                                                   NROWS, FF, EMBED, ffn_b1, nullptr);

    // 11. ffn2 (MFMA) + bias + resid x1 -> ores f32
    gemm_mfma<4><<<dim3(6, 16), blk, 0, stream>>>(fbf, wf2b, ores, nullptr,
                                                  NROWS, EMBED, FF, ffn_b2, x1);

    // 12. LN2 -> out
    layernorm_k<<<NROWS, blk, 0, stream>>>(ores, ln2_w, ln2_b, out, nullptr);
}

// Round 5
// 252.116 us; speedup vs baseline: 7.7345x; 1.2787x over previous
//
#include <hip/hip_runtime.h>
#include <math.h>

#define EMBED 768
#define DI 1536
#define DSTATE 16
#define DCONV 4
#define DTRANK 48
#define FF 3072
#define BATCH 2
#define SEQ 1024
#define NROWS (BATCH*SEQ)
#define TCH 64
#define NCH (SEQ/TCH)

typedef __bf16 bf16x8 __attribute__((ext_vector_type(8)));
typedef float f32x4 __attribute__((ext_vector_type(4)));
typedef unsigned int u32x4 __attribute__((ext_vector_type(4)));

static __device__ __forceinline__ unsigned short f2b(float f) {
    union { float f; unsigned u; } v; v.f = f;
    unsigned r = v.u + 0x7FFFu + ((v.u >> 16) & 1u);
    return (unsigned short)(r >> 16);
}
static __device__ __forceinline__ float b2f(unsigned short s) {
    union { unsigned u; float f; } v; v.u = ((unsigned)s) << 16;
    return v.f;
}

#define GLOAD_LDS16(g, l) __builtin_amdgcn_global_load_lds( \
    (const __attribute__((address_space(1))) void*)(g), \
    (__attribute__((address_space(3))) void*)(l), 16, 0, 0)

// ---------------------------------------------------------------------------
// gemm_sk: C[M,N] = A[M,K](bf16) @ W[N,K](bf16)^T, 128x64 tile, BK=32,
// global_load_lds staging with XOR-swizzled LDS (swizzle applied to BOTH the
// per-lane global source column and the ds_read offset — linear LDS dest).
// 4 waves; wave owns 32(M)x64(N): 2x4 frags of 16x16x32.
// KSPLIT>1: writes f32 partials to part[z][M][N].
// EPI (KSPLIT==1): 1 softplus(acc+bias)->C ; 3 gelu(acc+bias)->Cb(bf16) ;
//                  5 split col<DI -> C f32 (stride DI), else Cb bf16
// ---------------------------------------------------------------------------
template<int EPI, int KSPLIT>
__global__ __launch_bounds__(256)
void gemm_sk(const unsigned short* __restrict__ A,
             const unsigned short* __restrict__ W,
             float* __restrict__ C, unsigned short* __restrict__ Cb,
             float* __restrict__ part,
             int M, int N, int K,
             const float* __restrict__ bias)
{
    __shared__ alignas(16) unsigned short As[128 * 32];   // 8192 B linear
    __shared__ alignas(16) unsigned short Ws[64 * 32];    // 4096 B linear
    const int tid  = threadIdx.x;
    const int lane = tid & 63, wave = tid >> 6;
    const int bm = blockIdx.y * 128, bn = blockIdx.x * 64;
    const int kc = K / KSPLIT;
    const int kz = blockIdx.z * kc;
    const int ln = lane & 15, lg = lane >> 4;

    f32x4 acc[2][4];
    #pragma unroll
    for (int i = 0; i < 2; ++i)
        #pragma unroll
        for (int j = 0; j < 4; ++j)
            acc[i][j] = (f32x4){0.f, 0.f, 0.f, 0.f};

    // staging geometry: idx -> row = idx/4, 16B-unit c16 = idx&3
    // swizzled source col (shorts): c16*8 ^ ((row&3)<<3)
    const int ra = tid >> 2, ca = tid & 3;
    const int cs = (ca * 8) ^ ((ra & 3) << 3);   // rows ra and ra+64 share (row&3)
    const unsigned short* gA0 = A + (size_t)(bm + ra) * K + kz + cs;
    const unsigned short* gA1 = A + (size_t)(bm + ra + 64) * K + kz + cs;
    const unsigned short* gW  = W + (size_t)(bn + ra) * K + kz + cs;
    unsigned short* ldsA0 = As + wave * 512;          // idx = wave*64+lane
    unsigned short* ldsA1 = As + 2048 + wave * 512;   // idx = 256+wave*64+lane
    unsigned short* ldsW  = Ws + wave * 512;

    for (int k0 = 0; k0 < kc; k0 += 32) {
        GLOAD_LDS16(gA0 + k0, ldsA0);
        GLOAD_LDS16(gA1 + k0, ldsA1);
        GLOAD_LDS16(gW  + k0, ldsW);
        __syncthreads();                      // drains vmcnt before barrier
        bf16x8 af[2], wf[4];
        #pragma unroll
        for (int i = 0; i < 2; ++i) {
            int row = wave * 32 + i * 16 + ln;
            af[i] = *reinterpret_cast<const bf16x8*>(
                &As[row * 32 + ((lg * 8) ^ ((row & 3) << 3))]);
        }
        #pragma unroll
        for (int j = 0; j < 4; ++j) {
            int row = j * 16 + ln;
            wf[j] = *reinterpret_cast<const bf16x8*>(
                &Ws[row * 32 + ((lg * 8) ^ ((row & 3) << 3))]);
        }
        #pragma unroll
        for (int i = 0; i < 2; ++i)
            #pragma unroll
            for (int j = 0; j < 4; ++j)
                acc[i][j] = __builtin_amdgcn_mfma_f32_16x16x32_bf16(af[i], wf[j], acc[i][j], 0, 0, 0);
        __syncthreads();
    }

    if constexpr (KSPLIT > 1) {
        float* pb = part + (size_t)blockIdx.z * M * N;
        #pragma unroll
        for (int i = 0; i < 2; ++i)
            #pragma unroll
            for (int j = 0; j < 4; ++j) {
                int col = bn + j * 16 + ln;
                #pragma unroll
                for (int rr = 0; rr < 4; ++rr) {
                    int row = bm + wave * 32 + i * 16 + lg * 4 + rr;
                    pb[(size_t)row * N + col] = acc[i][j][rr];
                }
            }
    } else {
        #pragma unroll
        for (int i = 0; i < 2; ++i)
            #pragma unroll
            for (int j = 0; j < 4; ++j) {
                int col = bn + j * 16 + ln;
                #pragma unroll
                for (int rr = 0; rr < 4; ++rr) {
                    int row = bm + wave * 32 + i * 16 + lg * 4 + rr;
                    float v = acc[i][j][rr];
                    size_t o = (size_t)row * N + col;
                    if (EPI == 1) {
                        v += bias[col];
                        C[o] = (v > 20.f) ? v : log1pf(expf(v));
                    } else if (EPI == 3) {
                        v += bias[col];
                        float t = 0.7978845608028654f * (v + 0.044715f * v * v * v);
                        Cb[o] = f2b(0.5f * v * (1.f + tanhf(t)));
                    } else if (EPI == 5) {
                        if (col < DI) C[(size_t)row * DI + col] = v;
                        else          Cb[(size_t)row * DI + col - DI] = f2b(v);
                    } else {
                        C[o] = v;
                    }
                }
            }
    }
}

// ---------------------------------------------------------------------------
// Split-K reduce + epilogue. EPI: 2 +resid ; 4 +bias+resid.
// ---------------------------------------------------------------------------
template<int KS, int EPI>
__global__ __launch_bounds__(256)
void reduce_k(const float* __restrict__ part, float* __restrict__ C,
              const float* __restrict__ bias, const float* __restrict__ resid,
              int MN, int N)
{
    int i4 = (blockIdx.x * 256 + threadIdx.x) * 4;
    float4 s = *reinterpret_cast<const float4*>(part + i4);
    #pragma unroll
    for (int z = 1; z < KS; ++z) {
        float4 p = *reinterpret_cast<const float4*>(part + (size_t)z * MN + i4);
        s.x += p.x; s.y += p.y; s.z += p.z; s.w += p.w;
    }
    float4 r = *reinterpret_cast<const float4*>(resid + i4);
    if (EPI == 4) {
        int col = i4 % N;
        s.x += bias[col];     s.y += bias[col + 1];
        s.z += bias[col + 2]; s.w += bias[col + 3];
    }
    s.x += r.x; s.y += r.y; s.z += r.z; s.w += r.w;
    *reinterpret_cast<float4*>(C + i4) = s;
}

// ---------------------------------------------------------------------------
// x_proj split-K MFMA: part[s][M][80] = xcb[M, s*192..+192] @ W[80, ...]^T
// ---------------------------------------------------------------------------
__global__ __launch_bounds__(256)
void xproj_mfma(const unsigned short* __restrict__ A,
                const unsigned short* __restrict__ W,
                float* __restrict__ part)
{
    const int mt = blockIdx.x, s = blockIdx.y;
    const int lane = threadIdx.x & 63, wave = threadIdx.x >> 6;
    const int ln = lane & 15, lg = lane >> 4;
    const int row0 = mt * 128 + wave * 32;
    const int kb = s * 192;
    f32x4 acc[2][5];
    #pragma unroll
    for (int i = 0; i < 2; ++i)
        #pragma unroll
        for (int j = 0; j < 5; ++j)
            acc[i][j] = (f32x4){0.f, 0.f, 0.f, 0.f};

    for (int kk = 0; kk < 192; kk += 32) {
        const int k = kb + kk + lg * 8;
        bf16x8 af[2], wf[5];
        af[0] = *reinterpret_cast<const bf16x8*>(A + (size_t)(row0 + ln) * DI + k);
        af[1] = *reinterpret_cast<const bf16x8*>(A + (size_t)(row0 + 16 + ln) * DI + k);
        #pragma unroll
        for (int j = 0; j < 5; ++j)
            wf[j] = *reinterpret_cast<const bf16x8*>(W + (size_t)(j * 16 + ln) * DI + k);
        #pragma unroll
        for (int i = 0; i < 2; ++i)
            #pragma unroll
            for (int j = 0; j < 5; ++j)
                acc[i][j] = __builtin_amdgcn_mfma_f32_16x16x32_bf16(af[i], wf[j], acc[i][j], 0, 0, 0);
    }
    float* pb = part + (size_t)s * NROWS * 80;
    #pragma unroll
    for (int i = 0; i < 2; ++i)
        #pragma unroll
        for (int j = 0; j < 5; ++j)
            #pragma unroll
            for (int rr = 0; rr < 4; ++rr) {
                int row = row0 + i * 16 + lg * 4 + rr;
                int col = j * 16 + ln;
                pb[(size_t)row * 80 + col] = acc[i][j][rr];
            }
}

__global__ __launch_bounds__(256)
void xproj_reduce(const float* __restrict__ part, float* __restrict__ xdbl,
                  unsigned short* __restrict__ xdblb)
{
    int idx = blockIdx.x * 256 + threadIdx.x;      // 163840
    float sum = 0.f;
    #pragma unroll
    for (int s = 0; s < 8; ++s) sum += part[(size_t)s * NROWS * 80 + idx];
    xdbl[idx] = sum;
    int col = idx % 80, row = idx / 80;
    if (col < 48)      xdblb[row * 64 + col] = f2b(sum);
    else if (col < 64) xdblb[row * 64 + col] = 0;
}

// ---------------------------------------------------------------------------
// f32 -> bf16 conversions
// ---------------------------------------------------------------------------
__global__ __launch_bounds__(256)
void cvt6_k(const float* __restrict__ x,  const float* __restrict__ w1,
            const float* __restrict__ w2, const float* __restrict__ w3,
            const float* __restrict__ w4, const float* __restrict__ w5,
            unsigned short* __restrict__ xb,  unsigned short* __restrict__ w1b,
            unsigned short* __restrict__ w2b, unsigned short* __restrict__ w3b,
            unsigned short* __restrict__ w4b, unsigned short* __restrict__ w5b)
{
    size_t i4 = ((size_t)blockIdx.x * 256 + threadIdx.x) * 4;
    const float* src; unsigned short* dst; size_t off;
    if      (i4 < 1572864u) { src = x;  dst = xb;  off = i4; }
    else if (i4 < 3932160u) { src = w1; dst = w1b; off = i4 - 1572864u; }
    else if (i4 < 5111808u) { src = w2; dst = w2b; off = i4 - 3932160u; }
    else if (i4 < 7471104u) { src = w3; dst = w3b; off = i4 - 5111808u; }
    else if (i4 < 9830400u) { src = w4; dst = w4b; off = i4 - 7471104u; }
    else                    { src = w5; dst = w5b; off = i4 - 9830400u; }
    float4 v = *reinterpret_cast<const float4*>(src + off);
    ushort4 u;
    u.x = f2b(v.x); u.y = f2b(v.y); u.z = f2b(v.z); u.w = f2b(v.w);
    *reinterpret_cast<ushort4*>(dst + off) = u;
}

__global__ __launch_bounds__(256)
void cvt_dtw(const float* __restrict__ w, unsigned short* __restrict__ wb)
{
    int idx = blockIdx.x * 256 + threadIdx.x;      // 98304
    int row = idx >> 6, col = idx & 63;
    wb[idx] = (col < 48) ? f2b(w[row * 48 + col]) : (unsigned short)0;
}

// ---------------------------------------------------------------------------
// Causal depthwise conv(4) + bias + SiLU (native exp).
// ---------------------------------------------------------------------------
__global__ __launch_bounds__(256)
void conv_silu_k(const float* __restrict__ xin, const float* __restrict__ cw,
                 const float* __restrict__ cb, float* __restrict__ xc,
                 unsigned short* __restrict__ xcb)
{
    int idx = blockIdx.x * 256 + threadIdx.x;
    int d  = idx % DI;
    int bt = idx / DI;
    int t  = bt % SEQ, b = bt / SEQ;
    float w0 = cw[d*4], w1 = cw[d*4+1], w2 = cw[d*4+2], w3 = cw[d*4+3];
    const float* base = xin + ((size_t)b * SEQ) * DI + d;
    float acc = cb[d];
    if (t >= 3) acc += w0 * base[(size_t)(t - 3) * DI];
    if (t >= 2) acc += w1 * base[(size_t)(t - 2) * DI];
    if (t >= 1) acc += w2 * base[(size_t)(t - 1) * DI];
    acc += w3 * base[(size_t)t * DI];
    float v = acc / (1.f + __expf(-acc));
    xc[idx] = v;
    xcb[idx] = f2b(v);
}

// ---------------------------------------------------------------------------
// Chunked SSM scan, phase A (TCH=64).
// ---------------------------------------------------------------------------
__global__ __launch_bounds__(256)
void scan_a(const float* __restrict__ delta, const float* __restrict__ xc,
            const float* __restrict__ xdbl,  const float* __restrict__ A_log,
            float* __restrict__ hfin, float* __restrict__ aprod)
{
    const int dblk = blockIdx.x, ch = blockIdx.y, b = blockIdx.z;
    const int d0 = dblk * 16, t0 = ch * TCH;
    __shared__ float del_s[TCH][17];
    __shared__ float xcs[TCH][17];
    __shared__ float b_s[TCH][16];
    const int tid = threadIdx.x;
    const int sr = tid >> 4, sc = tid & 15;
    #pragma unroll
    for (int p = 0; p < 4; ++p) {
        int t = p * 16 + sr;
        size_t rowo = (size_t)(b * SEQ + t0 + t);
        del_s[t][sc] = delta[rowo * DI + d0 + sc];
        xcs[t][sc]   = xc[rowo * DI + d0 + sc];
        b_s[t][sc]   = xdbl[rowo * 80 + DTRANK + sc];
    }
    __syncthreads();
    const int lane = tid & 63, wave = tid >> 6;
    const int wd = wave * 4 + (lane >> 4), n = lane & 15;
    const int d = d0 + wd;
    const float Adn = -__expf(A_log[d * DSTATE + n]);
    float h = 0.f, ap = 1.f;
    #pragma unroll 4
    for (int t = 0; t < TCH; ++t) {
        float dl = del_s[t][wd];
        float dA = __expf(dl * Adn);
        h = dA * h + dl * b_s[t][n] * xcs[t][wd];
        ap *= dA;
    }
    size_t o = ((size_t)(b * NCH + ch) * DI + d) * DSTATE + n;
    hfin[o] = h; aprod[o] = ap;
}

// ---------------------------------------------------------------------------
// Phase B: serial combine over 16 chunks -> h0 per chunk.
// ---------------------------------------------------------------------------
__global__ __launch_bounds__(256)
void scan_b(const float* __restrict__ hfin, const float* __restrict__ aprod,
            float* __restrict__ h0)
{
    int idx = blockIdx.x * 256 + threadIdx.x;      // 49152
    int n = idx & 15;
    int d = (idx >> 4) % DI;
    int b = idx / (DI * DSTATE);
    float h = 0.f;
    #pragma unroll
    for (int ch = 0; ch < NCH; ++ch) {
        size_t o = ((size_t)(b * NCH + ch) * DI + d) * DSTATE + n;
        h0[o] = h;
        h = aprod[o] * h + hfin[o];
    }
}

// ---------------------------------------------------------------------------
// Phase C: start from h0, run chunk, produce gated bf16 y.
// ---------------------------------------------------------------------------
__global__ __launch_bounds__(256)
void scan_c(const float* __restrict__ delta, const float* __restrict__ xc,
            const float* __restrict__ xdbl,  const float* __restrict__ A_log,
            const float* __restrict__ Dp,    const unsigned short* __restrict__ zb,
            const float* __restrict__ h0,
            unsigned short* __restrict__ yb)
{
    const int dblk = blockIdx.x, ch = blockIdx.y, b = blockIdx.z;
    const int d0 = dblk * 16, t0 = ch * TCH;
    __shared__ float del_s[TCH][17];
    __shared__ float xcs[TCH][17];
    __shared__ float b_s[TCH][16];
    __shared__ float c_s[TCH][16];
    __shared__ float z_s[TCH][17];
    __shared__ unsigned short y_s[TCH][16];
    const int tid = threadIdx.x;
    const int sr = tid >> 4, sc = tid & 15;
    #pragma unroll
    for (int p = 0; p < 4; ++p) {
        int t = p * 16 + sr;
        size_t rowo = (size_t)(b * SEQ + t0 + t);
        del_s[t][sc] = delta[rowo * DI + d0 + sc];
        xcs[t][sc]   = xc[rowo * DI + d0 + sc];
        b_s[t][sc]   = xdbl[rowo * 80 + DTRANK + sc];
        c_s[t][sc]   = xdbl[rowo * 80 + DTRANK + DSTATE + sc];
        z_s[t][sc]   = b2f(zb[rowo * DI + d0 + sc]);
    }
    __syncthreads();
    const int lane = tid & 63, wave = tid >> 6;
    const int wd = wave * 4 + (lane >> 4), n = lane & 15;
    const int d = d0 + wd;
    const float Adn = -__expf(A_log[d * DSTATE + n]);
    const float Dd = Dp[d];
    float h = h0[((size_t)(b * NCH + ch) * DI + d) * DSTATE + n];
    #pragma unroll 4
    for (int t = 0; t < TCH; ++t) {
        float dl = del_s[t][wd], xv = xcs[t][wd];
        float dA = __expf(dl * Adn);
        h = dA * h + dl * b_s[t][n] * xv;
        float py = h * c_s[t][n];
        py += __shfl_xor(py, 1);
        py += __shfl_xor(py, 2);
        py += __shfl_xor(py, 4);
        py += __shfl_xor(py, 8);
        if (n == 0) {
            float yv = py + xv * Dd;
            float zv = z_s[t][wd];
            y_s[t][wd] = f2b(yv * zv / (1.f + __expf(-zv)));
        }
    }
    __syncthreads();
    #pragma unroll
    for (int p = 0; p < 4; ++p) {
        int t = p * 16 + sr;
        yb[(size_t)(b * SEQ + t0 + t) * DI + d0 + sc] = y_s[t][sc];
    }
}

// ---------------------------------------------------------------------------
// LayerNorm over 768, optional bf16 secondary output.
// ---------------------------------------------------------------------------
__global__ __launch_bounds__(256)
void layernorm_k(const float* __restrict__ in, const float* __restrict__ w,
                 const float* __restrict__ bb, float* __restrict__ out,
                 unsigned short* __restrict__ outb)
{
    const int row = blockIdx.x;
    const float* xr = in + (size_t)row * EMBED;
    const int i0 = threadIdx.x, i1 = i0 + 256, i2 = i0 + 512;
    float v0 = xr[i0], v1 = xr[i1], v2 = xr[i2];
    float s  = v0 + v1 + v2;
    float s2 = v0 * v0 + v1 * v1 + v2 * v2;
    #pragma unroll
    for (int m = 1; m < 64; m <<= 1) {
        s  += __shfl_xor(s,  m);
        s2 += __shfl_xor(s2, m);
    }
    __shared__ float sh1[4], sh2[4];
    int wv = threadIdx.x >> 6;
    if ((threadIdx.x & 63) == 0) { sh1[wv] = s; sh2[wv] = s2; }
    __syncthreads();
    float S1 = sh1[0] + sh1[1] + sh1[2] + sh1[3];
    float S2 = sh2[0] + sh2[1] + sh2[2] + sh2[3];
    float mu  = S1 * (1.f / EMBED);
    float var = S2 * (1.f / EMBED) - mu * mu;
    float rs  = rsqrtf(var + 1e-5f);
    float* orow = out + (size_t)row * EMBED;
    float o0 = (v0 - mu) * rs * w[i0] + bb[i0];
    float o1 = (v1 - mu) * rs * w[i1] + bb[i1];
    float o2 = (v2 - mu) * rs * w[i2] + bb[i2];
    orow[i0] = o0; orow[i1] = o1; orow[i2] = o2;
    if (outb) {
        unsigned short* obr = outb + (size_t)row * EMBED;
        obr[i0] = f2b(o0); obr[i1] = f2b(o1); obr[i2] = f2b(o2);
    }
}

// ---------------------------------------------------------------------------
extern "C" void kernel_launch(void* const* d_in, const int* in_sizes, int n_in,
                              void* d_out, int out_size, void* d_ws, size_t ws_size,
                              hipStream_t stream)
{
    const float* x         = (const float*)d_in[0];
    const float* in_proj_w = (const float*)d_in[1];
    const float* conv_w    = (const float*)d_in[2];
    const float* conv_b    = (const float*)d_in[3];
    const float* x_proj_w  = (const float*)d_in[4];
    const float* dt_proj_w = (const float*)d_in[5];
    const float* dt_proj_b = (const float*)d_in[6];
    const float* A_log     = (const float*)d_in[7];
    const float* D_param   = (const float*)d_in[8];
    const float* out_proj_w= (const float*)d_in[9];
    const float* ln1_w     = (const float*)d_in[10];
    const float* ln1_b     = (const float*)d_in[11];
    const float* ln2_w     = (const float*)d_in[12];
    const float* ln2_b     = (const float*)d_in[13];
    const float* ffn_w1    = (const float*)d_in[14];
    const float* ffn_b1    = (const float*)d_in[15];
    const float* ffn_w2    = (const float*)d_in[16];
    const float* ffn_b2    = (const float*)d_in[17];
    float* out = (float*)d_out;

    char* Wp = (char*)d_ws;
    // static regions (lifetimes in step numbers)
    float*          xin   = (float*)         (Wp + 0);          // [2-3]
    unsigned short* zbuf  = (unsigned short*)(Wp + 12582912);   // [2-7]
    float*          xc    = (float*)         (Wp + 18874368);   // [3-7]
    float*          xdbl  = (float*)         (Wp + 31457280);   // [4b-7]
    float*          delta = (float*)         (Wp + 32112640);   // [5-7]
    unsigned short* ybb   = (unsigned short*)(Wp + 44695552);   // [7-8]
    float*          hres  = (float*)         (Wp + 50987008);   // [8b-9]
    unsigned short* xb    = (unsigned short*)(Wp + 58851328);   // [1-2]
    unsigned short* wib   = (unsigned short*)(Wp + 61997056);   // [1-2]
    unsigned short* wob   = (unsigned short*)(Wp + 66715648);   // [1-8]
    unsigned short* wf1b  = (unsigned short*)(Wp + 69074944);   // [1-10]
    unsigned short* wf2b  = (unsigned short*)(Wp + 73793536);   // [1-11]
    // aliases into dead regions:
    unsigned short* fbf   = (unsigned short*)(Wp + 0);          // [10-11] (xin/part_op dead)
    float*          ores  = (float*)         (Wp + 12582912);   // [11b-12] (zbuf dead)
    float*          x1    = (float*)         (Wp + 32112640);   // [9-11b]  (delta dead)
    unsigned short* x1b   = (unsigned short*)(Wp + 58851328);   // [9-10]  (xb dead)
    float*          part  = (float*)         (Wp + 0);          // [4a-4b] (xin dead)
    unsigned short* xdblb = (unsigned short*)(Wp + 5242880);    // [4b-5]  (xin dead)
    unsigned short* xcb   = (unsigned short*)(Wp + 58851328);   // [3-4a]  (xb/wib dead)
    unsigned short* xpwb  = (unsigned short*)(Wp + 50987008);   // [1-4a]  (hres later)
    unsigned short* wdtb  = (unsigned short*)(Wp + 51232768);   // [1-5]   (hres later)
    float*          hfin  = (float*)         (Wp + 57278464);   // [6-6b]
    float*          aprod = (float*)         (Wp + 60424192);   // [6-6b]
    float*          h0    = (float*)         (Wp + 63569920);   // [6b-7]
    // split-K partials:
    float*          part_op = (float*)       (Wp + 0);          // [8a-8b] 25.2MB ([0,31.4M) dead after scan_c)
    float*          part_f2 = (float*)       (Wp + 38404096);   // [11a-11b] 25.2MB (x1 ends 38404096; wf2b at 73793536)

    dim3 blk(256);

    // 1. bf16 conversions
    cvt6_k<<<9720, blk, 0, stream>>>(x, in_proj_w, out_proj_w, ffn_w1, ffn_w2, x_proj_w,
                                     xb, wib, wob, wf1b, wf2b, xpwb);
    cvt_dtw<<<384, blk, 0, stream>>>(dt_proj_w, wdtb);

    // 2. in_proj: xin f32 + z bf16   [2048,3072] K=768
    gemm_sk<5, 1><<<dim3(48, 16, 1), blk, 0, stream>>>(xb, wib, xin, zbuf, nullptr,
                                                       NROWS, 2 * DI, EMBED, nullptr);

    // 3. conv + silu -> xc f32 + xcb bf16
    conv_silu_k<<<(BATCH * SEQ * DI) / 256, blk, 0, stream>>>(xin, conv_w, conv_b, xc, xcb);

    // 4. x_proj split-K MFMA + reduce
    xproj_mfma<<<dim3(16, 8), blk, 0, stream>>>(xcb, xpwb, part);
    xproj_reduce<<<640, blk, 0, stream>>>(part, xdbl, xdblb);

    // 5. dt_proj + softplus -> delta f32   [2048,1536] K=64
    gemm_sk<1, 1><<<dim3(24, 16, 1), blk, 0, stream>>>(xdblb, wdtb, delta, nullptr, nullptr,
                                                       NROWS, DI, 64, dt_proj_b);

    // 6. chunked scan
    scan_a<<<dim3(96, NCH, BATCH), blk, 0, stream>>>(delta, xc, xdbl, A_log, hfin, aprod);
    scan_b<<<192, blk, 0, stream>>>(hfin, aprod, h0);
    scan_c<<<dim3(96, NCH, BATCH), blk, 0, stream>>>(delta, xc, xdbl, A_log, D_param, zbuf,
                                                     h0, ybb);

    // 8. out_proj split-K(4) + reduce(+resid x) -> hres   [2048,768] K=1536
    gemm_sk<0, 4><<<dim3(12, 16, 4), blk, 0, stream>>>(ybb, wob, nullptr, nullptr, part_op,
                                                       NROWS, EMBED, DI, nullptr);
    reduce_k<4, 2><<<1536, blk, 0, stream>>>(part_op, hres, nullptr, x,
                                             NROWS * EMBED, EMBED);

    // 9. LN1 -> x1 f32 + x1b bf16
    layernorm_k<<<NROWS, blk, 0, stream>>>(hres, ln1_w, ln1_b, x1, x1b);

    // 10. ffn1 + gelu -> fbf bf16   [2048,3072] K=768
    gemm_sk<3, 1><<<dim3(48, 16, 1), blk, 0, stream>>>(x1b, wf1b, nullptr, fbf, nullptr,
                                                       NROWS, FF, EMBED, ffn_b1);

    // 11. ffn2 split-K(4) + reduce(+bias+resid x1) -> ores   [2048,768] K=3072
    gemm_sk<0, 4><<<dim3(12, 16, 4), blk, 0, stream>>>(fbf, wf2b, nullptr, nullptr, part_f2,
                                                       NROWS, EMBED, FF, nullptr);
    reduce_k<4, 4><<<1536, blk, 0, stream>>>(part_f2, ores, ffn_b2, x1,
                                             NROWS * EMBED, EMBED);

    // 12. LN2 -> out
    layernorm_k<<<NROWS, blk, 0, stream>>>(ores, ln2_w, ln2_b, out, nullptr);
}

// Round 6
// 226.257 us; speedup vs baseline: 8.6185x; 1.1143x over previous
//
#include <hip/hip_runtime.h>
#include <math.h>

#define EMBED 768
#define DI 1536
#define DSTATE 16
#define DCONV 4
#define DTRANK 48
#define FF 3072
#define BATCH 2
#define SEQ 1024
#define NROWS (BATCH*SEQ)
#define TCH 64
#define NCH (SEQ/TCH)
#define DBLK 64

typedef __bf16 bf16x8 __attribute__((ext_vector_type(8)));
typedef float f32x4 __attribute__((ext_vector_type(4)));
typedef unsigned int u32x4 __attribute__((ext_vector_type(4)));

static __device__ __forceinline__ unsigned short f2b(float f) {
    union { float f; unsigned u; } v; v.f = f;
    unsigned r = v.u + 0x7FFFu + ((v.u >> 16) & 1u);
    return (unsigned short)(r >> 16);
}
static __device__ __forceinline__ float b2f(unsigned short s) {
    union { unsigned u; float f; } v; v.u = ((unsigned)s) << 16;
    return v.f;
}

#define GLOAD_LDS16(g, l) __builtin_amdgcn_global_load_lds( \
    (const __attribute__((address_space(1))) void*)(g), \
    (__attribute__((address_space(3))) void*)(l), 16, 0, 0)

// ---------------------------------------------------------------------------
// gemm_sk: C[M,N] = A[M,K](bf16) @ W[N,K](bf16)^T, 128x64 tile, BK=32,
// global_load_lds staging, XOR swizzle applied to both global source col and
// ds_read offset. KSPLIT>1 writes f32 partials.
// ---------------------------------------------------------------------------
template<int EPI, int KSPLIT>
__global__ __launch_bounds__(256)
void gemm_sk(const unsigned short* __restrict__ A,
             const unsigned short* __restrict__ W,
             float* __restrict__ C, unsigned short* __restrict__ Cb,
             float* __restrict__ part,
             int M, int N, int K,
             const float* __restrict__ bias)
{
    __shared__ alignas(16) unsigned short As[128 * 32];
    __shared__ alignas(16) unsigned short Ws[64 * 32];
    const int tid  = threadIdx.x;
    const int lane = tid & 63, wave = tid >> 6;
    const int bm = blockIdx.y * 128, bn = blockIdx.x * 64;
    const int kc = K / KSPLIT;
    const int kz = blockIdx.z * kc;
    const int ln = lane & 15, lg = lane >> 4;

    f32x4 acc[2][4];
    #pragma unroll
    for (int i = 0; i < 2; ++i)
        #pragma unroll
        for (int j = 0; j < 4; ++j)
            acc[i][j] = (f32x4){0.f, 0.f, 0.f, 0.f};

    const int ra = tid >> 2, ca = tid & 3;
    const int cs = (ca * 8) ^ ((ra & 3) << 3);
    const unsigned short* gA0 = A + (size_t)(bm + ra) * K + kz + cs;
    const unsigned short* gA1 = A + (size_t)(bm + ra + 64) * K + kz + cs;
    const unsigned short* gW  = W + (size_t)(bn + ra) * K + kz + cs;
    unsigned short* ldsA0 = As + wave * 512;
    unsigned short* ldsA1 = As + 2048 + wave * 512;
    unsigned short* ldsW  = Ws + wave * 512;

    for (int k0 = 0; k0 < kc; k0 += 32) {
        GLOAD_LDS16(gA0 + k0, ldsA0);
        GLOAD_LDS16(gA1 + k0, ldsA1);
        GLOAD_LDS16(gW  + k0, ldsW);
        __syncthreads();
        bf16x8 af[2], wf[4];
        #pragma unroll
        for (int i = 0; i < 2; ++i) {
            int row = wave * 32 + i * 16 + ln;
            af[i] = *reinterpret_cast<const bf16x8*>(
                &As[row * 32 + ((lg * 8) ^ ((row & 3) << 3))]);
        }
        #pragma unroll
        for (int j = 0; j < 4; ++j) {
            int row = j * 16 + ln;
            wf[j] = *reinterpret_cast<const bf16x8*>(
                &Ws[row * 32 + ((lg * 8) ^ ((row & 3) << 3))]);
        }
        #pragma unroll
        for (int i = 0; i < 2; ++i)
            #pragma unroll
            for (int j = 0; j < 4; ++j)
                acc[i][j] = __builtin_amdgcn_mfma_f32_16x16x32_bf16(af[i], wf[j], acc[i][j], 0, 0, 0);
        __syncthreads();
    }

    if constexpr (KSPLIT > 1) {
        float* pb = part + (size_t)blockIdx.z * M * N;
        #pragma unroll
        for (int i = 0; i < 2; ++i)
            #pragma unroll
            for (int j = 0; j < 4; ++j) {
                int col = bn + j * 16 + ln;
                #pragma unroll
                for (int rr = 0; rr < 4; ++rr) {
                    int row = bm + wave * 32 + i * 16 + lg * 4 + rr;
                    pb[(size_t)row * N + col] = acc[i][j][rr];
                }
            }
    } else {
        #pragma unroll
        for (int i = 0; i < 2; ++i)
            #pragma unroll
            for (int j = 0; j < 4; ++j) {
                int col = bn + j * 16 + ln;
                #pragma unroll
                for (int rr = 0; rr < 4; ++rr) {
                    int row = bm + wave * 32 + i * 16 + lg * 4 + rr;
                    float v = acc[i][j][rr];
                    size_t o = (size_t)row * N + col;
                    if (EPI == 1) {
                        v += bias[col];
                        C[o] = (v > 20.f) ? v : log1pf(expf(v));
                    } else if (EPI == 3) {
                        v += bias[col];
                        float t = 0.7978845608028654f * (v + 0.044715f * v * v * v);
                        Cb[o] = f2b(0.5f * v * (1.f + tanhf(t)));
                    } else if (EPI == 5) {
                        if (col < DI) C[(size_t)row * DI + col] = v;
                        else          Cb[(size_t)row * DI + col - DI] = f2b(v);
                    } else {
                        C[o] = v;
                    }
                }
            }
    }
}

// ---------------------------------------------------------------------------
// Split-K reduce + epilogue. EPI: 2 +resid ; 4 +bias+resid.
// ---------------------------------------------------------------------------
template<int KS, int EPI>
__global__ __launch_bounds__(256)
void reduce_k(const float* __restrict__ part, float* __restrict__ C,
              const float* __restrict__ bias, const float* __restrict__ resid,
              int MN, int N)
{
    int i4 = (blockIdx.x * 256 + threadIdx.x) * 4;
    float4 s = *reinterpret_cast<const float4*>(part + i4);
    #pragma unroll
    for (int z = 1; z < KS; ++z) {
        float4 p = *reinterpret_cast<const float4*>(part + (size_t)z * MN + i4);
        s.x += p.x; s.y += p.y; s.z += p.z; s.w += p.w;
    }
    float4 r = *reinterpret_cast<const float4*>(resid + i4);
    if (EPI == 4) {
        int col = i4 % N;
        s.x += bias[col];     s.y += bias[col + 1];
        s.z += bias[col + 2]; s.w += bias[col + 3];
    }
    s.x += r.x; s.y += r.y; s.z += r.z; s.w += r.w;
    *reinterpret_cast<float4*>(C + i4) = s;
}

// ---------------------------------------------------------------------------
// x_proj split-K MFMA + reduce
// ---------------------------------------------------------------------------
__global__ __launch_bounds__(256)
void xproj_mfma(const unsigned short* __restrict__ A,
                const unsigned short* __restrict__ W,
                float* __restrict__ part)
{
    const int mt = blockIdx.x, s = blockIdx.y;
    const int lane = threadIdx.x & 63, wave = threadIdx.x >> 6;
    const int ln = lane & 15, lg = lane >> 4;
    const int row0 = mt * 128 + wave * 32;
    const int kb = s * 192;
    f32x4 acc[2][5];
    #pragma unroll
    for (int i = 0; i < 2; ++i)
        #pragma unroll
        for (int j = 0; j < 5; ++j)
            acc[i][j] = (f32x4){0.f, 0.f, 0.f, 0.f};

    for (int kk = 0; kk < 192; kk += 32) {
        const int k = kb + kk + lg * 8;
        bf16x8 af[2], wf[5];
        af[0] = *reinterpret_cast<const bf16x8*>(A + (size_t)(row0 + ln) * DI + k);
        af[1] = *reinterpret_cast<const bf16x8*>(A + (size_t)(row0 + 16 + ln) * DI + k);
        #pragma unroll
        for (int j = 0; j < 5; ++j)
            wf[j] = *reinterpret_cast<const bf16x8*>(W + (size_t)(j * 16 + ln) * DI + k);
        #pragma unroll
        for (int i = 0; i < 2; ++i)
            #pragma unroll
            for (int j = 0; j < 5; ++j)
                acc[i][j] = __builtin_amdgcn_mfma_f32_16x16x32_bf16(af[i], wf[j], acc[i][j], 0, 0, 0);
    }
    float* pb = part + (size_t)s * NROWS * 80;
    #pragma unroll
    for (int i = 0; i < 2; ++i)
        #pragma unroll
        for (int j = 0; j < 5; ++j)
            #pragma unroll
            for (int rr = 0; rr < 4; ++rr) {
                int row = row0 + i * 16 + lg * 4 + rr;
                int col = j * 16 + ln;
                pb[(size_t)row * 80 + col] = acc[i][j][rr];
            }
}

__global__ __launch_bounds__(256)
void xproj_reduce(const float* __restrict__ part, float* __restrict__ xdbl,
                  unsigned short* __restrict__ xdblb)
{
    int idx = blockIdx.x * 256 + threadIdx.x;      // 163840
    float sum = 0.f;
    #pragma unroll
    for (int s = 0; s < 8; ++s) sum += part[(size_t)s * NROWS * 80 + idx];
    xdbl[idx] = sum;
    int col = idx % 80, row = idx / 80;
    if (col < 48)      xdblb[row * 64 + col] = f2b(sum);
    else if (col < 64) xdblb[row * 64 + col] = 0;
}

// ---------------------------------------------------------------------------
// f32 -> bf16 conversions
// ---------------------------------------------------------------------------
__global__ __launch_bounds__(256)
void cvt6_k(const float* __restrict__ x,  const float* __restrict__ w1,
            const float* __restrict__ w2, const float* __restrict__ w3,
            const float* __restrict__ w4, const float* __restrict__ w5,
            unsigned short* __restrict__ xb,  unsigned short* __restrict__ w1b,
            unsigned short* __restrict__ w2b, unsigned short* __restrict__ w3b,
            unsigned short* __restrict__ w4b, unsigned short* __restrict__ w5b)
{
    size_t i4 = ((size_t)blockIdx.x * 256 + threadIdx.x) * 4;
    const float* src; unsigned short* dst; size_t off;
    if      (i4 < 1572864u) { src = x;  dst = xb;  off = i4; }
    else if (i4 < 3932160u) { src = w1; dst = w1b; off = i4 - 1572864u; }
    else if (i4 < 5111808u) { src = w2; dst = w2b; off = i4 - 3932160u; }
    else if (i4 < 7471104u) { src = w3; dst = w3b; off = i4 - 5111808u; }
    else if (i4 < 9830400u) { src = w4; dst = w4b; off = i4 - 7471104u; }
    else                    { src = w5; dst = w5b; off = i4 - 9830400u; }
    float4 v = *reinterpret_cast<const float4*>(src + off);
    ushort4 u;
    u.x = f2b(v.x); u.y = f2b(v.y); u.z = f2b(v.z); u.w = f2b(v.w);
    *reinterpret_cast<ushort4*>(dst + off) = u;
}

__global__ __launch_bounds__(256)
void cvt_dtw(const float* __restrict__ w, unsigned short* __restrict__ wb)
{
    int idx = blockIdx.x * 256 + threadIdx.x;      // 98304
    int row = idx >> 6, col = idx & 63;
    wb[idx] = (col < 48) ? f2b(w[row * 48 + col]) : (unsigned short)0;
}

// ---------------------------------------------------------------------------
// Causal depthwise conv(4) + bias + SiLU, 4 channels per thread (float4).
// ---------------------------------------------------------------------------
__global__ __launch_bounds__(256)
void conv_silu_k(const float* __restrict__ xin, const float* __restrict__ cw,
                 const float* __restrict__ cb, float* __restrict__ xc,
                 unsigned short* __restrict__ xcb)
{
    int q = blockIdx.x * 256 + threadIdx.x;        // over B*L*DI/4
    int d4 = (q * 4) % DI;
    int bt = (q * 4) / DI;
    int t  = bt % SEQ, b = bt / SEQ;
    const float* base = xin + ((size_t)b * SEQ + t) * DI + d4;
    float4 s3 = *reinterpret_cast<const float4*>(base);                       // tap w3 (t)
    float4 acc = *reinterpret_cast<const float4*>(cb + d4);
    // weights: cw[d][0..3]
    float4 wv0 = *reinterpret_cast<const float4*>(cw + (d4 + 0) * 4);
    float4 wv1 = *reinterpret_cast<const float4*>(cw + (d4 + 1) * 4);
    float4 wv2 = *reinterpret_cast<const float4*>(cw + (d4 + 2) * 4);
    float4 wv3 = *reinterpret_cast<const float4*>(cw + (d4 + 3) * 4);
    acc.x += wv0.w * s3.x; acc.y += wv1.w * s3.y; acc.z += wv2.w * s3.z; acc.w += wv3.w * s3.w;
    if (t >= 1) {
        float4 s = *reinterpret_cast<const float4*>(base - DI);
        acc.x += wv0.z * s.x; acc.y += wv1.z * s.y; acc.z += wv2.z * s.z; acc.w += wv3.z * s.w;
    }
    if (t >= 2) {
        float4 s = *reinterpret_cast<const float4*>(base - 2 * DI);
        acc.x += wv0.y * s.x; acc.y += wv1.y * s.y; acc.z += wv2.y * s.z; acc.w += wv3.y * s.w;
    }
    if (t >= 3) {
        float4 s = *reinterpret_cast<const float4*>(base - 3 * DI);
        acc.x += wv0.x * s.x; acc.y += wv1.x * s.y; acc.z += wv2.x * s.z; acc.w += wv3.x * s.w;
    }
    float4 v;
    v.x = acc.x / (1.f + __expf(-acc.x));
    v.y = acc.y / (1.f + __expf(-acc.y));
    v.z = acc.z / (1.f + __expf(-acc.z));
    v.w = acc.w / (1.f + __expf(-acc.w));
    size_t o = (size_t)bt * DI + d4;
    *reinterpret_cast<float4*>(xc + o) = v;
    ushort4 u; u.x = f2b(v.x); u.y = f2b(v.y); u.z = f2b(v.z); u.w = f2b(v.w);
    *reinterpret_cast<ushort4*>(xcb + o) = u;
}

// ---------------------------------------------------------------------------
// scan2_a: per-chunk local scan, n-quad per thread. Block covers 64 d.
// grid (DI/64, NCH, BATCH), 256 thr. No reduce.
// ---------------------------------------------------------------------------
__global__ __launch_bounds__(256)
void scan2_a(const float* __restrict__ delta, const float* __restrict__ xc,
             const float* __restrict__ xdbl,  const float* __restrict__ A_log,
             float* __restrict__ hfin, float* __restrict__ aprod)
{
    const int d0 = blockIdx.x * DBLK, ch = blockIdx.y, b = blockIdx.z;
    const int t0 = ch * TCH;
    __shared__ float del_s[TCH][DBLK + 4];
    __shared__ float xc_s[TCH][DBLK + 4];
    __shared__ float b_s[TCH][20];
    const int tid = threadIdx.x;
    {
        const int c4 = tid & 15, tr = tid >> 4;
        #pragma unroll
        for (int p = 0; p < 4; ++p) {
            int t = p * 16 + tr;
            size_t rowo = (size_t)(b * SEQ + t0 + t);
            *reinterpret_cast<float4*>(&del_s[t][c4 * 4]) =
                *reinterpret_cast<const float4*>(&delta[rowo * DI + d0 + c4 * 4]);
            *reinterpret_cast<float4*>(&xc_s[t][c4 * 4]) =
                *reinterpret_cast<const float4*>(&xc[rowo * DI + d0 + c4 * 4]);
        }
        const int cbq = tid & 3, tb = tid >> 2;
        size_t rowo = (size_t)(b * SEQ + t0 + tb);
        *reinterpret_cast<float4*>(&b_s[tb][cbq * 4]) =
            *reinterpret_cast<const float4*>(&xdbl[rowo * 80 + DTRANK + cbq * 4]);
    }
    __syncthreads();
    const int lane = tid & 63, wave = tid >> 6;
    const int wd = wave * 16 + (lane >> 2);
    const int d = d0 + wd;
    const int nq = (lane & 3) * 4;
    float4 Av = *reinterpret_cast<const float4*>(&A_log[d * DSTATE + nq]);
    const float A0 = -__expf(Av.x), A1 = -__expf(Av.y), A2 = -__expf(Av.z), A3 = -__expf(Av.w);
    float h0_ = 0.f, h1_ = 0.f, h2_ = 0.f, h3_ = 0.f;
    float p0 = 1.f, p1 = 1.f, p2 = 1.f, p3 = 1.f;
    #pragma unroll 4
    for (int t = 0; t < TCH; ++t) {
        float dl = del_s[t][wd];
        float u  = dl * xc_s[t][wd];
        float4 bq = *reinterpret_cast<const float4*>(&b_s[t][nq]);
        float e0 = __expf(dl * A0), e1 = __expf(dl * A1);
        float e2 = __expf(dl * A2), e3 = __expf(dl * A3);
        h0_ = e0 * h0_ + u * bq.x; p0 *= e0;
        h1_ = e1 * h1_ + u * bq.y; p1 *= e1;
        h2_ = e2 * h2_ + u * bq.z; p2 *= e2;
        h3_ = e3 * h3_ + u * bq.w; p3 *= e3;
    }
    size_t o = ((size_t)((b * NCH + ch) * DI) + d) * DSTATE + nq;
    *reinterpret_cast<float4*>(&hfin[o])  = (float4){h0_, h1_, h2_, h3_};
    *reinterpret_cast<float4*>(&aprod[o]) = (float4){p0, p1, p2, p3};
}

// ---------------------------------------------------------------------------
// scan2_b: serial combine over chunks, float4 per thread (one n-quad).
// ---------------------------------------------------------------------------
__global__ __launch_bounds__(256)
void scan2_b(const float* __restrict__ hfin, const float* __restrict__ aprod,
             float* __restrict__ h0)
{
    int idx = blockIdx.x * 256 + threadIdx.x;      // B*DI*4 = 12288
    int nq = (idx & 3) * 4;
    int d  = (idx >> 2) % DI;
    int b  = (idx >> 2) / DI;
    float4 h = {0.f, 0.f, 0.f, 0.f};
    #pragma unroll
    for (int ch = 0; ch < NCH; ++ch) {
        size_t o = ((size_t)((b * NCH + ch) * DI) + d) * DSTATE + nq;
        *reinterpret_cast<float4*>(&h0[o]) = h;
        float4 a = *reinterpret_cast<const float4*>(&aprod[o]);
        float4 f = *reinterpret_cast<const float4*>(&hfin[o]);
        h.x = a.x * h.x + f.x; h.y = a.y * h.y + f.y;
        h.z = a.z * h.z + f.z; h.w = a.w * h.w + f.w;
    }
}

// ---------------------------------------------------------------------------
// scan2_c: full scan from h0 with reduce + gate, n-quad per thread.
// ---------------------------------------------------------------------------
__global__ __launch_bounds__(256)
void scan2_c(const float* __restrict__ delta, const float* __restrict__ xc,
             const float* __restrict__ xdbl,  const float* __restrict__ A_log,
             const float* __restrict__ Dp,    const unsigned short* __restrict__ zb,
             const float* __restrict__ h0,
             unsigned short* __restrict__ yb)
{
    const int d0 = blockIdx.x * DBLK, ch = blockIdx.y, b = blockIdx.z;
    const int t0 = ch * TCH;
    __shared__ float del_s[TCH][DBLK + 4];
    __shared__ float xc_s[TCH][DBLK + 4];
    __shared__ float b_s[TCH][20];
    __shared__ float c_s[TCH][20];
    __shared__ unsigned short z_s[TCH][DBLK + 8];
    const int tid = threadIdx.x;
    {
        const int c4 = tid & 15, tr = tid >> 4;
        #pragma unroll
        for (int p = 0; p < 4; ++p) {
            int t = p * 16 + tr;
            size_t rowo = (size_t)(b * SEQ + t0 + t);
            *reinterpret_cast<float4*>(&del_s[t][c4 * 4]) =
                *reinterpret_cast<const float4*>(&delta[rowo * DI + d0 + c4 * 4]);
            *reinterpret_cast<float4*>(&xc_s[t][c4 * 4]) =
                *reinterpret_cast<const float4*>(&xc[rowo * DI + d0 + c4 * 4]);
        }
        const int cbq = tid & 3, tb = tid >> 2;
        size_t rowo = (size_t)(b * SEQ + t0 + tb);
        *reinterpret_cast<float4*>(&b_s[tb][cbq * 4]) =
            *reinterpret_cast<const float4*>(&xdbl[rowo * 80 + DTRANK + cbq * 4]);
        *reinterpret_cast<float4*>(&c_s[tb][cbq * 4]) =
            *reinterpret_cast<const float4*>(&xdbl[rowo * 80 + DTRANK + DSTATE + cbq * 4]);
        const int cz = tid & 7, tz = tid >> 3;
        #pragma unroll
        for (int p = 0; p < 2; ++p) {
            int t = p * 32 + tz;
            size_t rz = (size_t)(b * SEQ + t0 + t);
            *reinterpret_cast<u32x4*>(&z_s[t][cz * 8]) =
                *reinterpret_cast<const u32x4*>(&zb[rz * DI + d0 + cz * 8]);
        }
    }
    __syncthreads();
    const int lane = tid & 63, wave = tid >> 6;
    const int wd = wave * 16 + (lane >> 2);
    const int d = d0 + wd;
    const int nq = (lane & 3) * 4;
    float4 Av = *reinterpret_cast<const float4*>(&A_log[d * DSTATE + nq]);
    const float A0 = -__expf(Av.x), A1 = -__expf(Av.y), A2 = -__expf(Av.z), A3 = -__expf(Av.w);
    const float Dd = Dp[d];
    float4 h = *reinterpret_cast<const float4*>(
        &h0[((size_t)((b * NCH + ch) * DI) + d) * DSTATE + nq]);
    unsigned short* yrow = yb + (size_t)(b * SEQ + t0) * DI + d;
    #pragma unroll 2
    for (int t = 0; t < TCH; ++t) {
        float dl = del_s[t][wd];
        float xv = xc_s[t][wd];
        float u  = dl * xv;
        float4 bq = *reinterpret_cast<const float4*>(&b_s[t][nq]);
        float4 cq = *reinterpret_cast<const float4*>(&c_s[t][nq]);
        float e0 = __expf(dl * A0), e1 = __expf(dl * A1);
        float e2 = __expf(dl * A2), e3 = __expf(dl * A3);
        h.x = e0 * h.x + u * bq.x;
        h.y = e1 * h.y + u * bq.y;
        h.z = e2 * h.z + u * bq.z;
        h.w = e3 * h.w + u * bq.w;
        float py = h.x * cq.x + h.y * cq.y + h.z * cq.z + h.w * cq.w;
        py += __shfl_xor(py, 1);
        py += __shfl_xor(py, 2);
        if ((lane & 3) == 0) {
            float yv = py + xv * Dd;
            float zv = b2f(z_s[t][wd]);
            yv *= zv / (1.f + __expf(-zv));
            yrow[(size_t)t * DI] = f2b(yv);
        }
    }
}

// ---------------------------------------------------------------------------
// LayerNorm over 768, optional bf16 secondary output.
// ---------------------------------------------------------------------------
__global__ __launch_bounds__(256)
void layernorm_k(const float* __restrict__ in, const float* __restrict__ w,
                 const float* __restrict__ bb, float* __restrict__ out,
                 unsigned short* __restrict__ outb)
{
    const int row = blockIdx.x;
    const float* xr = in + (size_t)row * EMBED;
    const int i0 = threadIdx.x, i1 = i0 + 256, i2 = i0 + 512;
    float v0 = xr[i0], v1 = xr[i1], v2 = xr[i2];
    float s  = v0 + v1 + v2;
    float s2 = v0 * v0 + v1 * v1 + v2 * v2;
    #pragma unroll
    for (int m = 1; m < 64; m <<= 1) {
        s  += __shfl_xor(s,  m);
        s2 += __shfl_xor(s2, m);
    }
    __shared__ float sh1[4], sh2[4];
    int wv = threadIdx.x >> 6;
    if ((threadIdx.x & 63) == 0) { sh1[wv] = s; sh2[wv] = s2; }
    __syncthreads();
    float S1 = sh1[0] + sh1[1] + sh1[2] + sh1[3];
    float S2 = sh2[0] + sh2[1] + sh2[2] + sh2[3];
    float mu  = S1 * (1.f / EMBED);
    float var = S2 * (1.f / EMBED) - mu * mu;
    float rs  = rsqrtf(var + 1e-5f);
    float* orow = out + (size_t)row * EMBED;
    float o0 = (v0 - mu) * rs * w[i0] + bb[i0];
    float o1 = (v1 - mu) * rs * w[i1] + bb[i1];
    float o2 = (v2 - mu) * rs * w[i2] + bb[i2];
    orow[i0] = o0; orow[i1] = o1; orow[i2] = o2;
    if (outb) {
        unsigned short* obr = outb + (size_t)row * EMBED;
        obr[i0] = f2b(o0); obr[i1] = f2b(o1); obr[i2] = f2b(o2);
    }
}

// ---------------------------------------------------------------------------
extern "C" void kernel_launch(void* const* d_in, const int* in_sizes, int n_in,
                              void* d_out, int out_size, void* d_ws, size_t ws_size,
                              hipStream_t stream)
{
    const float* x         = (const float*)d_in[0];
    const float* in_proj_w = (const float*)d_in[1];
    const float* conv_w    = (const float*)d_in[2];
    const float* conv_b    = (const float*)d_in[3];
    const float* x_proj_w  = (const float*)d_in[4];
    const float* dt_proj_w = (const float*)d_in[5];
    const float* dt_proj_b = (const float*)d_in[6];
    const float* A_log     = (const float*)d_in[7];
    const float* D_param   = (const float*)d_in[8];
    const float* out_proj_w= (const float*)d_in[9];
    const float* ln1_w     = (const float*)d_in[10];
    const float* ln1_b     = (const float*)d_in[11];
    const float* ln2_w     = (const float*)d_in[12];
    const float* ln2_b     = (const float*)d_in[13];
    const float* ffn_w1    = (const float*)d_in[14];
    const float* ffn_b1    = (const float*)d_in[15];
    const float* ffn_w2    = (const float*)d_in[16];
    const float* ffn_b2    = (const float*)d_in[17];
    float* out = (float*)d_out;

    char* Wp = (char*)d_ws;
    float*          xin   = (float*)         (Wp + 0);          // [2-3]
    unsigned short* zbuf  = (unsigned short*)(Wp + 12582912);   // [2-7]
    float*          xc    = (float*)         (Wp + 18874368);   // [3-7]
    float*          xdbl  = (float*)         (Wp + 31457280);   // [4b-7]
    float*          delta = (float*)         (Wp + 32112640);   // [5-7]
    unsigned short* ybb   = (unsigned short*)(Wp + 44695552);   // [7-8]
    float*          hres  = (float*)         (Wp + 50987008);   // [8b-9]
    unsigned short* xb    = (unsigned short*)(Wp + 58851328);   // [1-2]
    unsigned short* wib   = (unsigned short*)(Wp + 61997056);   // [1-2]
    unsigned short* wob   = (unsigned short*)(Wp + 66715648);   // [1-8]
    unsigned short* wf1b  = (unsigned short*)(Wp + 69074944);   // [1-10]
    unsigned short* wf2b  = (unsigned short*)(Wp + 73793536);   // [1-11]
    unsigned short* fbf   = (unsigned short*)(Wp + 0);          // [10-11]
    float*          ores  = (float*)         (Wp + 12582912);   // [11b-12]
    float*          x1    = (float*)         (Wp + 32112640);   // [9-11b]
    unsigned short* x1b   = (unsigned short*)(Wp + 58851328);   // [9-10]
    float*          part  = (float*)         (Wp + 0);          // [4a-4b]
    unsigned short* xdblb = (unsigned short*)(Wp + 5242880);    // [4b-5]
    unsigned short* xcb   = (unsigned short*)(Wp + 58851328);   // [3-4a]
    unsigned short* xpwb  = (unsigned short*)(Wp + 50987008);   // [1-4a]
    unsigned short* wdtb  = (unsigned short*)(Wp + 51232768);   // [1-5]
    float*          hfin  = (float*)         (Wp + 57278464);   // [6-6b]
    float*          aprod = (float*)         (Wp + 60424192);   // [6-6b]
    float*          h0    = (float*)         (Wp + 63569920);   // [6b-7]
    float*          part_op = (float*)       (Wp + 0);          // [8a-8b]
    float*          part_f2 = (float*)       (Wp + 38404096);   // [11a-11b]

    dim3 blk(256);

    // 1. bf16 conversions
    cvt6_k<<<9720, blk, 0, stream>>>(x, in_proj_w, out_proj_w, ffn_w1, ffn_w2, x_proj_w,
                                     xb, wib, wob, wf1b, wf2b, xpwb);
    cvt_dtw<<<384, blk, 0, stream>>>(dt_proj_w, wdtb);

    // 2. in_proj: xin f32 + z bf16
    gemm_sk<5, 1><<<dim3(48, 16, 1), blk, 0, stream>>>(xb, wib, xin, zbuf, nullptr,
                                                       NROWS, 2 * DI, EMBED, nullptr);

    // 3. conv + silu -> xc f32 + xcb bf16
    conv_silu_k<<<(BATCH * SEQ * DI) / 1024, blk, 0, stream>>>(xin, conv_w, conv_b, xc, xcb);

    // 4. x_proj split-K MFMA + reduce
    xproj_mfma<<<dim3(16, 8), blk, 0, stream>>>(xcb, xpwb, part);
    xproj_reduce<<<640, blk, 0, stream>>>(part, xdbl, xdblb);

    // 5. dt_proj + softplus -> delta f32
    gemm_sk<1, 1><<<dim3(24, 16, 1), blk, 0, stream>>>(xdblb, wdtb, delta, nullptr, nullptr,
                                                       NROWS, DI, 64, dt_proj_b);

    // 6. chunked scan (n-quad per thread)
    scan2_a<<<dim3(DI / DBLK, NCH, BATCH), blk, 0, stream>>>(delta, xc, xdbl, A_log, hfin, aprod);
    scan2_b<<<48, blk, 0, stream>>>(hfin, aprod, h0);
    scan2_c<<<dim3(DI / DBLK, NCH, BATCH), blk, 0, stream>>>(delta, xc, xdbl, A_log, D_param,
                                                             zbuf, h0, ybb);

    // 8. out_proj split-K(4) + reduce(+resid x) -> hres
    gemm_sk<0, 4><<<dim3(12, 16, 4), blk, 0, stream>>>(ybb, wob, nullptr, nullptr, part_op,
                                                       NROWS, EMBED, DI, nullptr);
    reduce_k<4, 2><<<1536, blk, 0, stream>>>(part_op, hres, nullptr, x,
                                             NROWS * EMBED, EMBED);

    // 9. LN1 -> x1 f32 + x1b bf16
    layernorm_k<<<NROWS, blk, 0, stream>>>(hres, ln1_w, ln1_b, x1, x1b);

    // 10. ffn1 + gelu -> fbf bf16
    gemm_sk<3, 1><<<dim3(48, 16, 1), blk, 0, stream>>>(x1b, wf1b, nullptr, fbf, nullptr,
                                                       NROWS, FF, EMBED, ffn_b1);

    // 11. ffn2 split-K(4) + reduce(+bias+resid x1) -> ores
    gemm_sk<0, 4><<<dim3(12, 16, 4), blk, 0, stream>>>(fbf, wf2b, nullptr, nullptr, part_f2,
                                                       NROWS, EMBED, FF, nullptr);
    reduce_k<4, 4><<<1536, blk, 0, stream>>>(part_f2, ores, ffn_b2, x1,
                                             NROWS * EMBED, EMBED);

    // 12. LN2 -> out
    layernorm_k<<<NROWS, blk, 0, stream>>>(ores, ln2_w, ln2_b, out, nullptr);
}

// Round 7
// 217.614 us; speedup vs baseline: 8.9608x; 1.0397x over previous
//
#include <hip/hip_runtime.h>
#include <math.h>

#define EMBED 768
#define DI 1536
#define DSTATE 16
#define DCONV 4
#define DTRANK 48
#define FF 3072
#define BATCH 2
#define SEQ 1024
#define NROWS (BATCH*SEQ)
#define TCH 32
#define NCH (SEQ/TCH)
#define DBLK 64

typedef __bf16 bf16x8 __attribute__((ext_vector_type(8)));
typedef float f32x4 __attribute__((ext_vector_type(4)));
typedef unsigned int u32x4 __attribute__((ext_vector_type(4)));

static __device__ __forceinline__ unsigned short f2b(float f) {
    union { float f; unsigned u; } v; v.f = f;
    unsigned r = v.u + 0x7FFFu + ((v.u >> 16) & 1u);
    return (unsigned short)(r >> 16);
}
static __device__ __forceinline__ float b2f(unsigned short s) {
    union { unsigned u; float f; } v; v.u = ((unsigned)s) << 16;
    return v.f;
}

#define GLOAD_LDS16(g, l) __builtin_amdgcn_global_load_lds( \
    (const __attribute__((address_space(1))) void*)(g), \
    (__attribute__((address_space(3))) void*)(l), 16, 0, 0)

// ---------------------------------------------------------------------------
// gemm_sk: C[M,N] = A[M,K](bf16) @ W[N,K](bf16)^T, 128x64 tile, BK=32,
// global_load_lds staging, XOR swizzle on both global source col and ds_read.
// ---------------------------------------------------------------------------
template<int EPI, int KSPLIT>
__global__ __launch_bounds__(256)
void gemm_sk(const unsigned short* __restrict__ A,
             const unsigned short* __restrict__ W,
             float* __restrict__ C, unsigned short* __restrict__ Cb,
             float* __restrict__ part,
             int M, int N, int K,
             const float* __restrict__ bias)
{
    __shared__ alignas(16) unsigned short As[128 * 32];
    __shared__ alignas(16) unsigned short Ws[64 * 32];
    const int tid  = threadIdx.x;
    const int lane = tid & 63, wave = tid >> 6;
    const int bm = blockIdx.y * 128, bn = blockIdx.x * 64;
    const int kc = K / KSPLIT;
    const int kz = blockIdx.z * kc;
    const int ln = lane & 15, lg = lane >> 4;

    f32x4 acc[2][4];
    #pragma unroll
    for (int i = 0; i < 2; ++i)
        #pragma unroll
        for (int j = 0; j < 4; ++j)
            acc[i][j] = (f32x4){0.f, 0.f, 0.f, 0.f};

    const int ra = tid >> 2, ca = tid & 3;
    const int cs = (ca * 8) ^ ((ra & 3) << 3);
    const unsigned short* gA0 = A + (size_t)(bm + ra) * K + kz + cs;
    const unsigned short* gA1 = A + (size_t)(bm + ra + 64) * K + kz + cs;
    const unsigned short* gW  = W + (size_t)(bn + ra) * K + kz + cs;
    unsigned short* ldsA0 = As + wave * 512;
    unsigned short* ldsA1 = As + 2048 + wave * 512;
    unsigned short* ldsW  = Ws + wave * 512;

    for (int k0 = 0; k0 < kc; k0 += 32) {
        GLOAD_LDS16(gA0 + k0, ldsA0);
        GLOAD_LDS16(gA1 + k0, ldsA1);
        GLOAD_LDS16(gW  + k0, ldsW);
        __syncthreads();
        bf16x8 af[2], wf[4];
        #pragma unroll
        for (int i = 0; i < 2; ++i) {
            int row = wave * 32 + i * 16 + ln;
            af[i] = *reinterpret_cast<const bf16x8*>(
                &As[row * 32 + ((lg * 8) ^ ((row & 3) << 3))]);
        }
        #pragma unroll
        for (int j = 0; j < 4; ++j) {
            int row = j * 16 + ln;
            wf[j] = *reinterpret_cast<const bf16x8*>(
                &Ws[row * 32 + ((lg * 8) ^ ((row & 3) << 3))]);
        }
        #pragma unroll
        for (int i = 0; i < 2; ++i)
            #pragma unroll
            for (int j = 0; j < 4; ++j)
                acc[i][j] = __builtin_amdgcn_mfma_f32_16x16x32_bf16(af[i], wf[j], acc[i][j], 0, 0, 0);
        __syncthreads();
    }

    if constexpr (KSPLIT > 1) {
        float* pb = part + (size_t)blockIdx.z * M * N;
        #pragma unroll
        for (int i = 0; i < 2; ++i)
            #pragma unroll
            for (int j = 0; j < 4; ++j) {
                int col = bn + j * 16 + ln;
                #pragma unroll
                for (int rr = 0; rr < 4; ++rr) {
                    int row = bm + wave * 32 + i * 16 + lg * 4 + rr;
                    pb[(size_t)row * N + col] = acc[i][j][rr];
                }
            }
    } else {
        #pragma unroll
        for (int i = 0; i < 2; ++i)
            #pragma unroll
            for (int j = 0; j < 4; ++j) {
                int col = bn + j * 16 + ln;
                #pragma unroll
                for (int rr = 0; rr < 4; ++rr) {
                    int row = bm + wave * 32 + i * 16 + lg * 4 + rr;
                    float v = acc[i][j][rr];
                    size_t o = (size_t)row * N + col;
                    if (EPI == 1) {
                        v += bias[col];
                        C[o] = (v > 20.f) ? v : log1pf(expf(v));
                    } else if (EPI == 3) {
                        v += bias[col];
                        float t = 0.7978845608028654f * (v + 0.044715f * v * v * v);
                        Cb[o] = f2b(0.5f * v * (1.f + tanhf(t)));
                    } else if (EPI == 5) {
                        if (col < DI) C[(size_t)row * DI + col] = v;
                        else          Cb[(size_t)row * DI + col - DI] = f2b(v);
                    } else {
                        C[o] = v;
                    }
                }
            }
    }
}

// ---------------------------------------------------------------------------
// Split-K reduce + epilogue. EPI: 2 +resid ; 4 +bias+resid.
// ---------------------------------------------------------------------------
template<int KS, int EPI>
__global__ __launch_bounds__(256)
void reduce_k(const float* __restrict__ part, float* __restrict__ C,
              const float* __restrict__ bias, const float* __restrict__ resid,
              int MN, int N)
{
    int i4 = (blockIdx.x * 256 + threadIdx.x) * 4;
    float4 s = *reinterpret_cast<const float4*>(part + i4);
    #pragma unroll
    for (int z = 1; z < KS; ++z) {
        float4 p = *reinterpret_cast<const float4*>(part + (size_t)z * MN + i4);
        s.x += p.x; s.y += p.y; s.z += p.z; s.w += p.w;
    }
    float4 r = *reinterpret_cast<const float4*>(resid + i4);
    if (EPI == 4) {
        int col = i4 % N;
        s.x += bias[col];     s.y += bias[col + 1];
        s.z += bias[col + 2]; s.w += bias[col + 3];
    }
    s.x += r.x; s.y += r.y; s.z += r.z; s.w += r.w;
    *reinterpret_cast<float4*>(C + i4) = s;
}

// ---------------------------------------------------------------------------
// x_proj split-K MFMA + reduce
// ---------------------------------------------------------------------------
__global__ __launch_bounds__(256)
void xproj_mfma(const unsigned short* __restrict__ A,
                const unsigned short* __restrict__ W,
                float* __restrict__ part)
{
    const int mt = blockIdx.x, s = blockIdx.y;
    const int lane = threadIdx.x & 63, wave = threadIdx.x >> 6;
    const int ln = lane & 15, lg = lane >> 4;
    const int row0 = mt * 128 + wave * 32;
    const int kb = s * 192;
    f32x4 acc[2][5];
    #pragma unroll
    for (int i = 0; i < 2; ++i)
        #pragma unroll
        for (int j = 0; j < 5; ++j)
            acc[i][j] = (f32x4){0.f, 0.f, 0.f, 0.f};

    for (int kk = 0; kk < 192; kk += 32) {
        const int k = kb + kk + lg * 8;
        bf16x8 af[2], wf[5];
        af[0] = *reinterpret_cast<const bf16x8*>(A + (size_t)(row0 + ln) * DI + k);
        af[1] = *reinterpret_cast<const bf16x8*>(A + (size_t)(row0 + 16 + ln) * DI + k);
        #pragma unroll
        for (int j = 0; j < 5; ++j)
            wf[j] = *reinterpret_cast<const bf16x8*>(W + (size_t)(j * 16 + ln) * DI + k);
        #pragma unroll
        for (int i = 0; i < 2; ++i)
            #pragma unroll
            for (int j = 0; j < 5; ++j)
                acc[i][j] = __builtin_amdgcn_mfma_f32_16x16x32_bf16(af[i], wf[j], acc[i][j], 0, 0, 0);
    }
    float* pb = part + (size_t)s * NROWS * 80;
    #pragma unroll
    for (int i = 0; i < 2; ++i)
        #pragma unroll
        for (int j = 0; j < 5; ++j)
            #pragma unroll
            for (int rr = 0; rr < 4; ++rr) {
                int row = row0 + i * 16 + lg * 4 + rr;
                int col = j * 16 + ln;
                pb[(size_t)row * 80 + col] = acc[i][j][rr];
            }
}

__global__ __launch_bounds__(256)
void xproj_reduce(const float* __restrict__ part, float* __restrict__ xdbl,
                  unsigned short* __restrict__ xdblb)
{
    int idx = blockIdx.x * 256 + threadIdx.x;      // 163840
    float sum = 0.f;
    #pragma unroll
    for (int s = 0; s < 8; ++s) sum += part[(size_t)s * NROWS * 80 + idx];
    xdbl[idx] = sum;
    int col = idx % 80, row = idx / 80;
    if (col < 48)      xdblb[row * 64 + col] = f2b(sum);
    else if (col < 64) xdblb[row * 64 + col] = 0;
}

// ---------------------------------------------------------------------------
// f32 -> bf16 conversions
// ---------------------------------------------------------------------------
__global__ __launch_bounds__(256)
void cvt6_k(const float* __restrict__ x,  const float* __restrict__ w1,
            const float* __restrict__ w2, const float* __restrict__ w3,
            const float* __restrict__ w4, const float* __restrict__ w5,
            unsigned short* __restrict__ xb,  unsigned short* __restrict__ w1b,
            unsigned short* __restrict__ w2b, unsigned short* __restrict__ w3b,
            unsigned short* __restrict__ w4b, unsigned short* __restrict__ w5b)
{
    size_t i4 = ((size_t)blockIdx.x * 256 + threadIdx.x) * 4;
    const float* src; unsigned short* dst; size_t off;
    if      (i4 < 1572864u) { src = x;  dst = xb;  off = i4; }
    else if (i4 < 3932160u) { src = w1; dst = w1b; off = i4 - 1572864u; }
    else if (i4 < 5111808u) { src = w2; dst = w2b; off = i4 - 3932160u; }
    else if (i4 < 7471104u) { src = w3; dst = w3b; off = i4 - 5111808u; }
    else if (i4 < 9830400u) { src = w4; dst = w4b; off = i4 - 7471104u; }
    else                    { src = w5; dst = w5b; off = i4 - 9830400u; }
    float4 v = *reinterpret_cast<const float4*>(src + off);
    ushort4 u;
    u.x = f2b(v.x); u.y = f2b(v.y); u.z = f2b(v.z); u.w = f2b(v.w);
    *reinterpret_cast<ushort4*>(dst + off) = u;
}

__global__ __launch_bounds__(256)
void cvt_dtw(const float* __restrict__ w, unsigned short* __restrict__ wb)
{
    int idx = blockIdx.x * 256 + threadIdx.x;      // 98304
    int row = idx >> 6, col = idx & 63;
    wb[idx] = (col < 48) ? f2b(w[row * 48 + col]) : (unsigned short)0;
}

// ---------------------------------------------------------------------------
// Causal depthwise conv(4) + bias + SiLU, 4 channels per thread.
// ---------------------------------------------------------------------------
__global__ __launch_bounds__(256)
void conv_silu_k(const float* __restrict__ xin, const float* __restrict__ cw,
                 const float* __restrict__ cb, float* __restrict__ xc,
                 unsigned short* __restrict__ xcb)
{
    int q = blockIdx.x * 256 + threadIdx.x;
    int d4 = (q * 4) % DI;
    int bt = (q * 4) / DI;
    int t  = bt % SEQ, b = bt / SEQ;
    const float* base = xin + ((size_t)b * SEQ + t) * DI + d4;
    float4 s3 = *reinterpret_cast<const float4*>(base);
    float4 acc = *reinterpret_cast<const float4*>(cb + d4);
    float4 wv0 = *reinterpret_cast<const float4*>(cw + (d4 + 0) * 4);
    float4 wv1 = *reinterpret_cast<const float4*>(cw + (d4 + 1) * 4);
    float4 wv2 = *reinterpret_cast<const float4*>(cw + (d4 + 2) * 4);
    float4 wv3 = *reinterpret_cast<const float4*>(cw + (d4 + 3) * 4);
    acc.x += wv0.w * s3.x; acc.y += wv1.w * s3.y; acc.z += wv2.w * s3.z; acc.w += wv3.w * s3.w;
    if (t >= 1) {
        float4 s = *reinterpret_cast<const float4*>(base - DI);
        acc.x += wv0.z * s.x; acc.y += wv1.z * s.y; acc.z += wv2.z * s.z; acc.w += wv3.z * s.w;
    }
    if (t >= 2) {
        float4 s = *reinterpret_cast<const float4*>(base - 2 * DI);
        acc.x += wv0.y * s.x; acc.y += wv1.y * s.y; acc.z += wv2.y * s.z; acc.w += wv3.y * s.w;
    }
    if (t >= 3) {
        float4 s = *reinterpret_cast<const float4*>(base - 3 * DI);
        acc.x += wv0.x * s.x; acc.y += wv1.x * s.y; acc.z += wv2.x * s.z; acc.w += wv3.x * s.w;
    }
    float4 v;
    v.x = acc.x / (1.f + __expf(-acc.x));
    v.y = acc.y / (1.f + __expf(-acc.y));
    v.z = acc.z / (1.f + __expf(-acc.z));
    v.w = acc.w / (1.f + __expf(-acc.w));
    size_t o = (size_t)bt * DI + d4;
    *reinterpret_cast<float4*>(xc + o) = v;
    ushort4 u; u.x = f2b(v.x); u.y = f2b(v.y); u.z = f2b(v.z); u.w = f2b(v.w);
    *reinterpret_cast<ushort4*>(xcb + o) = u;
}

// ---------------------------------------------------------------------------
// scan2_a: per-chunk local scan (TCH=32), n-quad per thread.
// grid (DI/64, NCH, BATCH), 256 thr.
// ---------------------------------------------------------------------------
__global__ __launch_bounds__(256)
void scan2_a(const float* __restrict__ delta, const float* __restrict__ xc,
             const float* __restrict__ xdbl,  const float* __restrict__ A_log,
             float* __restrict__ hfin, float* __restrict__ aprod)
{
    const int d0 = blockIdx.x * DBLK, ch = blockIdx.y, b = blockIdx.z;
    const int t0 = ch * TCH;
    __shared__ float del_s[TCH][DBLK + 4];
    __shared__ float xc_s[TCH][DBLK + 4];
    __shared__ float b_s[TCH][20];
    const int tid = threadIdx.x;
    {
        const int c4 = tid & 15, tr = tid >> 4;
        #pragma unroll
        for (int p = 0; p < 2; ++p) {
            int t = p * 16 + tr;
            size_t rowo = (size_t)(b * SEQ + t0 + t);
            *reinterpret_cast<float4*>(&del_s[t][c4 * 4]) =
                *reinterpret_cast<const float4*>(&delta[rowo * DI + d0 + c4 * 4]);
            *reinterpret_cast<float4*>(&xc_s[t][c4 * 4]) =
                *reinterpret_cast<const float4*>(&xc[rowo * DI + d0 + c4 * 4]);
        }
        const int cbq = tid & 3, tb = tid >> 2;   // tb 0..63
        if (tb < TCH) {
            size_t rowo = (size_t)(b * SEQ + t0 + tb);
            *reinterpret_cast<float4*>(&b_s[tb][cbq * 4]) =
                *reinterpret_cast<const float4*>(&xdbl[rowo * 80 + DTRANK + cbq * 4]);
        }
    }
    __syncthreads();
    const int lane = tid & 63, wave = tid >> 6;
    const int wd = wave * 16 + (lane >> 2);
    const int d = d0 + wd;
    const int nq = (lane & 3) * 4;
    float4 Av = *reinterpret_cast<const float4*>(&A_log[d * DSTATE + nq]);
    const float A0 = -__expf(Av.x), A1 = -__expf(Av.y), A2 = -__expf(Av.z), A3 = -__expf(Av.w);
    float h0_ = 0.f, h1_ = 0.f, h2_ = 0.f, h3_ = 0.f;
    float p0 = 1.f, p1 = 1.f, p2 = 1.f, p3 = 1.f;
    #pragma unroll 4
    for (int t = 0; t < TCH; ++t) {
        float dl = del_s[t][wd];
        float u  = dl * xc_s[t][wd];
        float4 bq = *reinterpret_cast<const float4*>(&b_s[t][nq]);
        float e0 = __expf(dl * A0), e1 = __expf(dl * A1);
        float e2 = __expf(dl * A2), e3 = __expf(dl * A3);
        h0_ = e0 * h0_ + u * bq.x; p0 *= e0;
        h1_ = e1 * h1_ + u * bq.y; p1 *= e1;
        h2_ = e2 * h2_ + u * bq.z; p2 *= e2;
        h3_ = e3 * h3_ + u * bq.w; p3 *= e3;
    }
    size_t o = ((size_t)((b * NCH + ch) * DI) + d) * DSTATE + nq;
    *reinterpret_cast<float4*>(&hfin[o])  = (float4){h0_, h1_, h2_, h3_};
    *reinterpret_cast<float4*>(&aprod[o]) = (float4){p0, p1, p2, p3};
}

// ---------------------------------------------------------------------------
// scan2_b: serial combine over chunks, float4 per thread (one n-quad).
// ---------------------------------------------------------------------------
__global__ __launch_bounds__(256)
void scan2_b(const float* __restrict__ hfin, const float* __restrict__ aprod,
             float* __restrict__ h0)
{
    int idx = blockIdx.x * 256 + threadIdx.x;      // B*DI*4 = 12288
    int nq = (idx & 3) * 4;
    int d  = (idx >> 2) % DI;
    int b  = (idx >> 2) / DI;
    float4 h = {0.f, 0.f, 0.f, 0.f};
    #pragma unroll
    for (int ch = 0; ch < NCH; ++ch) {
        size_t o = ((size_t)((b * NCH + ch) * DI) + d) * DSTATE + nq;
        *reinterpret_cast<float4*>(&h0[o]) = h;
        float4 a = *reinterpret_cast<const float4*>(&aprod[o]);
        float4 f = *reinterpret_cast<const float4*>(&hfin[o]);
        h.x = a.x * h.x + f.x; h.y = a.y * h.y + f.y;
        h.z = a.z * h.z + f.z; h.w = a.w * h.w + f.w;
    }
}

// ---------------------------------------------------------------------------
// scan2_c: full scan from h0 with reduce + gate (TCH=32), n-quad per thread.
// ---------------------------------------------------------------------------
__global__ __launch_bounds__(256)
void scan2_c(const float* __restrict__ delta, const float* __restrict__ xc,
             const float* __restrict__ xdbl,  const float* __restrict__ A_log,
             const float* __restrict__ Dp,    const unsigned short* __restrict__ zb,
             const float* __restrict__ h0,
             unsigned short* __restrict__ yb)
{
    const int d0 = blockIdx.x * DBLK, ch = blockIdx.y, b = blockIdx.z;
    const int t0 = ch * TCH;
    __shared__ float del_s[TCH][DBLK + 4];
    __shared__ float xc_s[TCH][DBLK + 4];
    __shared__ float b_s[TCH][20];
    __shared__ float c_s[TCH][20];
    __shared__ unsigned short z_s[TCH][DBLK + 8];
    const int tid = threadIdx.x;
    {
        const int c4 = tid & 15, tr = tid >> 4;
        #pragma unroll
        for (int p = 0; p < 2; ++p) {
            int t = p * 16 + tr;
            size_t rowo = (size_t)(b * SEQ + t0 + t);
            *reinterpret_cast<float4*>(&del_s[t][c4 * 4]) =
                *reinterpret_cast<const float4*>(&delta[rowo * DI + d0 + c4 * 4]);
            *reinterpret_cast<float4*>(&xc_s[t][c4 * 4]) =
                *reinterpret_cast<const float4*>(&xc[rowo * DI + d0 + c4 * 4]);
        }
        const int cbq = tid & 3, tb = tid >> 2;   // tb 0..63
        if (tb < TCH) {
            size_t rowo = (size_t)(b * SEQ + t0 + tb);
            *reinterpret_cast<float4*>(&b_s[tb][cbq * 4]) =
                *reinterpret_cast<const float4*>(&xdbl[rowo * 80 + DTRANK + cbq * 4]);
        } else {
            size_t rowo = (size_t)(b * SEQ + t0 + tb - TCH);
            *reinterpret_cast<float4*>(&c_s[tb - TCH][cbq * 4]) =
                *reinterpret_cast<const float4*>(&xdbl[rowo * 80 + DTRANK + DSTATE + cbq * 4]);
        }
        const int cz = tid & 7, tz = tid >> 3;    // tz 0..31
        size_t rz = (size_t)(b * SEQ + t0 + tz);
        *reinterpret_cast<u32x4*>(&z_s[tz][cz * 8]) =
            *reinterpret_cast<const u32x4*>(&zb[rz * DI + d0 + cz * 8]);
    }
    __syncthreads();
    const int lane = tid & 63, wave = tid >> 6;
    const int wd = wave * 16 + (lane >> 2);
    const int d = d0 + wd;
    const int nq = (lane & 3) * 4;
    float4 Av = *reinterpret_cast<const float4*>(&A_log[d * DSTATE + nq]);
    const float A0 = -__expf(Av.x), A1 = -__expf(Av.y), A2 = -__expf(Av.z), A3 = -__expf(Av.w);
    const float Dd = Dp[d];
    float4 h = *reinterpret_cast<const float4*>(
        &h0[((size_t)((b * NCH + ch) * DI) + d) * DSTATE + nq]);
    unsigned short* yrow = yb + (size_t)(b * SEQ + t0) * DI + d;
    #pragma unroll 4
    for (int t = 0; t < TCH; ++t) {
        float dl = del_s[t][wd];
        float xv = xc_s[t][wd];
        float u  = dl * xv;
        float4 bq = *reinterpret_cast<const float4*>(&b_s[t][nq]);
        float4 cq = *reinterpret_cast<const float4*>(&c_s[t][nq]);
        float e0 = __expf(dl * A0), e1 = __expf(dl * A1);
        float e2 = __expf(dl * A2), e3 = __expf(dl * A3);
        h.x = e0 * h.x + u * bq.x;
        h.y = e1 * h.y + u * bq.y;
        h.z = e2 * h.z + u * bq.z;
        h.w = e3 * h.w + u * bq.w;
        float py = h.x * cq.x + h.y * cq.y + h.z * cq.z + h.w * cq.w;
        py += __shfl_xor(py, 1);
        py += __shfl_xor(py, 2);
        if ((lane & 3) == 0) {
            float yv = py + xv * Dd;
            float zv = b2f(z_s[t][wd]);
            yv *= zv / (1.f + __expf(-zv));
            yrow[(size_t)t * DI] = f2b(yv);
        }
    }
}

// ---------------------------------------------------------------------------
// LayerNorm over 768, optional bf16 secondary output.
// ---------------------------------------------------------------------------
__global__ __launch_bounds__(256)
void layernorm_k(const float* __restrict__ in, const float* __restrict__ w,
                 const float* __restrict__ bb, float* __restrict__ out,
                 unsigned short* __restrict__ outb)
{
    const int row = blockIdx.x;
    const float* xr = in + (size_t)row * EMBED;
    const int i0 = threadIdx.x, i1 = i0 + 256, i2 = i0 + 512;
    float v0 = xr[i0], v1 = xr[i1], v2 = xr[i2];
    float s  = v0 + v1 + v2;
    float s2 = v0 * v0 + v1 * v1 + v2 * v2;
    #pragma unroll
    for (int m = 1; m < 64; m <<= 1) {
        s  += __shfl_xor(s,  m);
        s2 += __shfl_xor(s2, m);
    }
    __shared__ float sh1[4], sh2[4];
    int wv = threadIdx.x >> 6;
    if ((threadIdx.x & 63) == 0) { sh1[wv] = s; sh2[wv] = s2; }
    __syncthreads();
    float S1 = sh1[0] + sh1[1] + sh1[2] + sh1[3];
    float S2 = sh2[0] + sh2[1] + sh2[2] + sh2[3];
    float mu  = S1 * (1.f / EMBED);
    float var = S2 * (1.f / EMBED) - mu * mu;
    float rs  = rsqrtf(var + 1e-5f);
    float* orow = out + (size_t)row * EMBED;
    float o0 = (v0 - mu) * rs * w[i0] + bb[i0];
    float o1 = (v1 - mu) * rs * w[i1] + bb[i1];
    float o2 = (v2 - mu) * rs * w[i2] + bb[i2];
    orow[i0] = o0; orow[i1] = o1; orow[i2] = o2;
    if (outb) {
        unsigned short* obr = outb + (size_t)row * EMBED;
        obr[i0] = f2b(o0); obr[i1] = f2b(o1); obr[i2] = f2b(o2);
    }
}

// ---------------------------------------------------------------------------
extern "C" void kernel_launch(void* const* d_in, const int* in_sizes, int n_in,
                              void* d_out, int out_size, void* d_ws, size_t ws_size,
                              hipStream_t stream)
{
    const float* x         = (const float*)d_in[0];
    const float* in_proj_w = (const float*)d_in[1];
    const float* conv_w    = (const float*)d_in[2];
    const float* conv_b    = (const float*)d_in[3];
    const float* x_proj_w  = (const float*)d_in[4];
    const float* dt_proj_w = (const float*)d_in[5];
    const float* dt_proj_b = (const float*)d_in[6];
    const float* A_log     = (const float*)d_in[7];
    const float* D_param   = (const float*)d_in[8];
    const float* out_proj_w= (const float*)d_in[9];
    const float* ln1_w     = (const float*)d_in[10];
    const float* ln1_b     = (const float*)d_in[11];
    const float* ln2_w     = (const float*)d_in[12];
    const float* ln2_b     = (const float*)d_in[13];
    const float* ffn_w1    = (const float*)d_in[14];
    const float* ffn_b1    = (const float*)d_in[15];
    const float* ffn_w2    = (const float*)d_in[16];
    const float* ffn_b2    = (const float*)d_in[17];
    float* out = (float*)d_out;

    char* Wp = (char*)d_ws;
    // static regions (lifetimes in step numbers)
    float*          xin   = (float*)         (Wp + 0);          // [2-3]
    unsigned short* zbuf  = (unsigned short*)(Wp + 12582912);   // [2-7]
    float*          xc    = (float*)         (Wp + 18874368);   // [3-7]
    float*          xdbl  = (float*)         (Wp + 31457280);   // [4b-7]
    float*          delta = (float*)         (Wp + 32112640);   // [5-7]
    unsigned short* ybb   = (unsigned short*)(Wp + 44695552);   // [7-8]
    float*          hres  = (float*)         (Wp + 50987008);   // [8b-9]
    unsigned short* xb    = (unsigned short*)(Wp + 58851328);   // [1-2]
    unsigned short* wib   = (unsigned short*)(Wp + 61997056);   // [1-2]
    unsigned short* wob   = (unsigned short*)(Wp + 66715648);   // [1-8]
    unsigned short* wf1b  = (unsigned short*)(Wp + 69074944);   // [1-10]
    unsigned short* wf2b  = (unsigned short*)(Wp + 73793536);   // [1-11]
    // aliases into dead regions:
    unsigned short* fbf   = (unsigned short*)(Wp + 0);          // [10-11]
    float*          ores  = (float*)         (Wp + 12582912);   // [11b-12]
    float*          x1    = (float*)         (Wp + 32112640);   // [9-11b]
    unsigned short* x1b   = (unsigned short*)(Wp + 58851328);   // [9-10]
    float*          part  = (float*)         (Wp + 0);          // [4a-4b]
    unsigned short* xdblb = (unsigned short*)(Wp + 5242880);    // [4b-5]
    unsigned short* xcb   = (unsigned short*)(Wp + 58851328);   // [3-4a]
    unsigned short* xpwb  = (unsigned short*)(Wp + 50987008);   // [1-4a]
    unsigned short* wdtb  = (unsigned short*)(Wp + 51232768);   // [1-5]
    // NCH=32 scan state: 6.29 MB each
    float*          hfin  = (float*)         (Wp + 0);          // [6a-6b] (xin/part/xdblb dead)
    float*          aprod = (float*)         (Wp + 6291456);    // [6a-6b]
    float*          h0    = (float*)         (Wp + 50987008);   // [6b-7] (xpwb/wdtb dead; hres written 8b)
    // split-K partials:
    float*          part_op = (float*)       (Wp + 0);          // [8a-8b]
    float*          part_f2 = (float*)       (Wp + 38404096);   // [11a-11b]

    dim3 blk(256);

    // 1. bf16 conversions
    cvt6_k<<<9720, blk, 0, stream>>>(x, in_proj_w, out_proj_w, ffn_w1, ffn_w2, x_proj_w,
                                     xb, wib, wob, wf1b, wf2b, xpwb);
    cvt_dtw<<<384, blk, 0, stream>>>(dt_proj_w, wdtb);

    // 2. in_proj: xin f32 + z bf16
    gemm_sk<5, 1><<<dim3(48, 16, 1), blk, 0, stream>>>(xb, wib, xin, zbuf, nullptr,
                                                       NROWS, 2 * DI, EMBED, nullptr);

    // 3. conv + silu -> xc f32 + xcb bf16
    conv_silu_k<<<(BATCH * SEQ * DI) / 1024, blk, 0, stream>>>(xin, conv_w, conv_b, xc, xcb);

    // 4. x_proj split-K MFMA + reduce
    xproj_mfma<<<dim3(16, 8), blk, 0, stream>>>(xcb, xpwb, part);
    xproj_reduce<<<640, blk, 0, stream>>>(part, xdbl, xdblb);

    // 5. dt_proj + softplus -> delta f32
    gemm_sk<1, 1><<<dim3(24, 16, 1), blk, 0, stream>>>(xdblb, wdtb, delta, nullptr, nullptr,
                                                       NROWS, DI, 64, dt_proj_b);

    // 6. chunked scan (TCH=32)
    scan2_a<<<dim3(DI / DBLK, NCH, BATCH), blk, 0, stream>>>(delta, xc, xdbl, A_log, hfin, aprod);
    scan2_b<<<48, blk, 0, stream>>>(hfin, aprod, h0);
    scan2_c<<<dim3(DI / DBLK, NCH, BATCH), blk, 0, stream>>>(delta, xc, xdbl, A_log, D_param,
                                                             zbuf, h0, ybb);

    // 8. out_proj split-K(4) + reduce(+resid x) -> hres
    gemm_sk<0, 4><<<dim3(12, 16, 4), blk, 0, stream>>>(ybb, wob, nullptr, nullptr, part_op,
                                                       NROWS, EMBED, DI, nullptr);
    reduce_k<4, 2><<<1536, blk, 0, stream>>>(part_op, hres, nullptr, x,
                                             NROWS * EMBED, EMBED);

    // 9. LN1 -> x1 f32 + x1b bf16
    layernorm_k<<<NROWS, blk, 0, stream>>>(hres, ln1_w, ln1_b, x1, x1b);

    // 10. ffn1 + gelu -> fbf bf16
    gemm_sk<3, 1><<<dim3(48, 16, 1), blk, 0, stream>>>(x1b, wf1b, nullptr, fbf, nullptr,
                                                       NROWS, FF, EMBED, ffn_b1);

    // 11. ffn2 split-K(4) + reduce(+bias+resid x1) -> ores
    gemm_sk<0, 4><<<dim3(12, 16, 4), blk, 0, stream>>>(fbf, wf2b, nullptr, nullptr, part_f2,
                                                       NROWS, EMBED, FF, nullptr);
    reduce_k<4, 4><<<1536, blk, 0, stream>>>(part_f2, ores, ffn_b2, x1,
                                             NROWS * EMBED, EMBED);

    // 12. LN2 -> out
    layernorm_k<<<NROWS, blk, 0, stream>>>(ores, ln2_w, ln2_b, out, nullptr);
}